// Round 7
// baseline (277.431 us; speedup 1.0000x reference)
//
#include <hip/hip_runtime.h>

// MPNN: h1 = relu(segsum(feat[src] -> dst) @ W1^T + b1)
//       out = segsum(h1[src] -> dst) @ W2^T + b2
// N=50000, E=800000, d=128.
//
// CSR by dst -> bf16 gather-side reduction -> W-stationary LDS linear.
// Round 6->7: fill_csr's random 4B scatter (52MB write-allocate traffic)
// replaced by 2-level counting sort: partition into 256-node buckets (dense
// appends), then per-bucket LDS sort into col (dense coalesced writes).

#define NDIM 128
#define SCAN_BS 512

__device__ inline unsigned short f2bf_rne(float x) {
    unsigned u = __float_as_uint(x);
    unsigned lsb = (u >> 16) & 1u;
    u += 0x7fffu + lsb;
    return (unsigned short)(u >> 16);
}

// ---------------- weight transpose ----------------
__global__ void transpose_w2(const float* __restrict__ W1, const float* __restrict__ W2,
                             float* __restrict__ WT1, float* __restrict__ WT2) {
    int tid = blockIdx.x * 256 + threadIdx.x;   // 32768 threads
    int which = tid >> 14;
    int t = tid & 16383;
    int o = t >> 7;
    int i = t & 127;
    if (which == 0) WT1[i * NDIM + o] = W1[o * NDIM + i];
    else            WT2[i * NDIM + o] = W2[o * NDIM + i];
}

// ---------------- f32 -> bf16 table conversion ----------------
__global__ void convert_bf(const float* __restrict__ in, unsigned short* __restrict__ out,
                           int n8) {
    int i = blockIdx.x * blockDim.x + threadIdx.x;
    if (i >= n8) return;
    const float4* p = reinterpret_cast<const float4*>(in + (size_t)i * 8);
    float4 a = p[0], b = p[1];
    uint4 pk;
    pk.x = (unsigned)f2bf_rne(a.x) | ((unsigned)f2bf_rne(a.y) << 16);
    pk.y = (unsigned)f2bf_rne(a.z) | ((unsigned)f2bf_rne(a.w) << 16);
    pk.z = (unsigned)f2bf_rne(b.x) | ((unsigned)f2bf_rne(b.y) << 16);
    pk.w = (unsigned)f2bf_rne(b.z) | ((unsigned)f2bf_rne(b.w) << 16);
    *reinterpret_cast<uint4*>(out + (size_t)i * 8) = pk;
}

// ---------------- CSR build ----------------
__global__ void hist_dst(const int* __restrict__ dst, int* __restrict__ counts, int n_edges) {
    int i = blockIdx.x * blockDim.x + threadIdx.x;
    if (i < n_edges) atomicAdd(&counts[dst[i]], 1);
}

__global__ __launch_bounds__(SCAN_BS) void scan_local(const int* __restrict__ counts,
                                                      int* __restrict__ row_ptr,
                                                      int* __restrict__ block_sums, int n) {
    __shared__ int sh[SCAN_BS];
    int t = threadIdx.x;
    int i = blockIdx.x * SCAN_BS + t;
    int v = (i < n) ? counts[i] : 0;
    sh[t] = v;
    __syncthreads();
    for (int off = 1; off < SCAN_BS; off <<= 1) {
        int u = (t >= off) ? sh[t - off] : 0;
        __syncthreads();
        sh[t] += u;
        __syncthreads();
    }
    if (i < n) row_ptr[i] = sh[t] - v;
    if (t == SCAN_BS - 1) block_sums[blockIdx.x] = sh[t];
}

__global__ __launch_bounds__(128) void scan_blocksums(int* __restrict__ block_sums, int nb) {
    __shared__ int sh[128];
    int t = threadIdx.x;
    sh[t] = (t < nb) ? block_sums[t] : 0;
    __syncthreads();
    for (int off = 1; off < 128; off <<= 1) {
        int u = (t >= off) ? sh[t - off] : 0;
        __syncthreads();
        sh[t] += u;
        __syncthreads();
    }
    if (t < nb) block_sums[t] = sh[t];
}

__global__ __launch_bounds__(SCAN_BS) void scan_apply(int* __restrict__ row_ptr,
                                                      int* __restrict__ cursor,
                                                      const int* __restrict__ block_sums,
                                                      int n, int nb) {
    int b = blockIdx.x;
    int i = b * SCAN_BS + threadIdx.x;
    int add = (b == 0) ? 0 : block_sums[b - 1];
    if (i < n) {
        int r = row_ptr[i] + add;
        row_ptr[i] = r;
        cursor[i]  = r;
    }
    if (i == 0) row_ptr[n] = block_sums[nb - 1];
}

// ---- two-level CSR fill ----
// bucket b covers nodes [b*256, b*256+256); bucket base = row_ptr[b*256].
// bcur padded to 16 ints (64B) per bucket to spread L2 atomic contention.
__global__ void init_bcur(const int* __restrict__ row_ptr, int* __restrict__ bcur, int nbk) {
    int b = blockIdx.x * blockDim.x + threadIdx.x;
    if (b < nbk) bcur[b * 16] = row_ptr[b << 8];
}

__global__ void partition_edges(const int* __restrict__ src, const int* __restrict__ dst,
                                int* __restrict__ bcur, int* __restrict__ bdata, int n_edges) {
    int i = blockIdx.x * blockDim.x + threadIdx.x;
    if (i >= n_edges) return;
    int d = dst[i];
    int s = src[i];
    int b = d >> 8;
    int pos = atomicAdd(&bcur[b * 16], 1);
    bdata[pos] = s | ((d & 255) << 16);     // requires n_nodes <= 65536
}

// one block per bucket: sort packed edges into col via LDS cursors.
__global__ __launch_bounds__(256) void bucket_sort(const int* __restrict__ row_ptr,
                                                   const int* __restrict__ bdata,
                                                   int* __restrict__ col,
                                                   int n_nodes) {
    __shared__ int lcur[256];
    int b = blockIdx.x;
    int node0 = b << 8;
    int t = threadIdx.x;
    int endn = min(node0 + 256, n_nodes);
    int base = row_ptr[node0];
    int cnt  = row_ptr[endn] - base;
    if (node0 + t < endn) lcur[t] = row_ptr[node0 + t] - base;
    __syncthreads();
    for (int i = t; i < cnt; i += 256) {
        int pack  = bdata[base + i];
        int local = pack >> 16;
        int s     = pack & 0xFFFF;
        int pos = atomicAdd(&lcur[local], 1);
        col[base + pos] = s;
    }
}

// ---- fallback direct fill (random scatter) ----
__global__ void fill_csr(const int* __restrict__ src, const int* __restrict__ dst,
                         int* __restrict__ cursor, int* __restrict__ col, int n_edges) {
    int i = blockIdx.x * blockDim.x + threadIdx.x;
    if (i < n_edges) {
        int pos = atomicAdd(&cursor[dst[i]], 1);
        col[pos] = src[i];
    }
}

// ---------------- bf16 gather-side segment sum ----------------
__global__ void aggregate_bf(const uint4* __restrict__ feat_bf,   // [N][16] uint4
                             const int* __restrict__ row_ptr,
                             const int* __restrict__ col,
                             float* __restrict__ out, int n_nodes) {
    int wid  = (blockIdx.x * blockDim.x + threadIdx.x) >> 6;
    int lane = threadIdx.x & 63;
    if (wid >= n_nodes) return;
    int sub = lane >> 4;            // edge slot 0..3
    int d   = lane & 15;            // 16B chunk within row
    int beg = row_ptr[wid];
    int end = row_ptr[wid + 1];
    float acc[8] = {0.f,0.f,0.f,0.f,0.f,0.f,0.f,0.f};

    int e = beg + sub;
    for (; e + 4 < end; e += 8) {
        int s0 = col[e];
        int s1 = col[e + 4];
        uint4 a = feat_bf[(size_t)s0 * 16 + d];
        uint4 b = feat_bf[(size_t)s1 * 16 + d];
        unsigned aw[4] = {a.x, a.y, a.z, a.w};
        unsigned bw[4] = {b.x, b.y, b.z, b.w};
#pragma unroll
        for (int j = 0; j < 4; ++j) {
            acc[2*j]   += __uint_as_float(aw[j] << 16);
            acc[2*j+1] += __uint_as_float(aw[j] & 0xFFFF0000u);
            acc[2*j]   += __uint_as_float(bw[j] << 16);
            acc[2*j+1] += __uint_as_float(bw[j] & 0xFFFF0000u);
        }
    }
    for (; e < end; e += 4) {
        int s0 = col[e];
        uint4 a = feat_bf[(size_t)s0 * 16 + d];
        unsigned aw[4] = {a.x, a.y, a.z, a.w};
#pragma unroll
        for (int j = 0; j < 4; ++j) {
            acc[2*j]   += __uint_as_float(aw[j] << 16);
            acc[2*j+1] += __uint_as_float(aw[j] & 0xFFFF0000u);
        }
    }
#pragma unroll
    for (int j = 0; j < 8; ++j) {
        acc[j] += __shfl_xor(acc[j], 16, 64);
        acc[j] += __shfl_xor(acc[j], 32, 64);
    }
    if (sub == 0) {
        float4 r0 = make_float4(acc[0], acc[1], acc[2], acc[3]);
        float4 r1 = make_float4(acc[4], acc[5], acc[6], acc[7]);
        float* op = out + (size_t)wid * NDIM + d * 8;
        *reinterpret_cast<float4*>(op)     = r0;
        *reinterpret_cast<float4*>(op + 4) = r1;
    }
}

// ---------------- f32 gather (fallback path) ----------------
__global__ void aggregate(const float* __restrict__ feat,
                          const int* __restrict__ row_ptr,
                          const int* __restrict__ col,
                          float* __restrict__ out, int n_nodes) {
    int wid  = (blockIdx.x * blockDim.x + threadIdx.x) >> 6;
    int lane = threadIdx.x & 63;
    if (wid >= n_nodes) return;
    int half = lane >> 5;
    int d4   = (lane & 31) << 2;
    int beg = row_ptr[wid];
    int end = row_ptr[wid + 1];
    float ax = 0.f, ay = 0.f, az = 0.f, aw = 0.f;
    float bx = 0.f, by = 0.f, bz = 0.f, bw = 0.f;
    int k = beg + half;
    for (; k + 2 < end; k += 4) {
        int s0 = col[k];
        int s1 = col[k + 2];
        float4 v0 = *reinterpret_cast<const float4*>(feat + (size_t)s0 * NDIM + d4);
        float4 v1 = *reinterpret_cast<const float4*>(feat + (size_t)s1 * NDIM + d4);
        ax += v0.x; ay += v0.y; az += v0.z; aw += v0.w;
        bx += v1.x; by += v1.y; bz += v1.z; bw += v1.w;
    }
    if (k < end) {
        int s0 = col[k];
        float4 v0 = *reinterpret_cast<const float4*>(feat + (size_t)s0 * NDIM + d4);
        ax += v0.x; ay += v0.y; az += v0.z; aw += v0.w;
    }
    ax += bx; ay += by; az += bz; aw += bw;
    ax += __shfl(ax, lane ^ 32, 64);
    ay += __shfl(ay, lane ^ 32, 64);
    az += __shfl(az, lane ^ 32, 64);
    aw += __shfl(aw, lane ^ 32, 64);
    if (half == 0) {
        float4 r; r.x = ax; r.y = ay; r.z = az; r.w = aw;
        *reinterpret_cast<float4*>(out + (size_t)wid * NDIM + d4) = r;
    }
}

// ---------------- W-stationary LDS-tiled linear ----------------
template <bool RELU, bool OUTBF>
__global__ __launch_bounds__(256) void linear_lds(const float* __restrict__ h,
                                                  const float* __restrict__ WT,
                                                  const float* __restrict__ bias,
                                                  float* __restrict__ out,
                                                  unsigned short* __restrict__ out_bf,
                                                  int n_nodes) {
    __shared__ float wt_s[32 * 128];        // [k][c]
    __shared__ float ht_s[32 * 132];        // [k][r], stride 132
    int t  = threadIdx.x;
    int ct = t & 15;
    int rt = t >> 4;
    int r0 = blockIdx.x * 128;

    float4 acc[8][2];
#pragma unroll
    for (int r = 0; r < 8; ++r) {
        acc[r][0] = make_float4(0.f, 0.f, 0.f, 0.f);
        acc[r][1] = make_float4(0.f, 0.f, 0.f, 0.f);
    }

    for (int kc = 0; kc < NDIM; kc += 32) {
        __syncthreads();
        {
            const float4* wsrc = reinterpret_cast<const float4*>(WT + kc * NDIM);
            float4* wdst = reinterpret_cast<float4*>(wt_s);
#pragma unroll
            for (int i = 0; i < 4; ++i) wdst[t + 256 * i] = wsrc[t + 256 * i];
        }
        {
            int rr = t >> 3;            // 0..31
            int kk = t & 7;             // 0..7
#pragma unroll
            for (int p = 0; p < 4; ++p) {
                int r = rr + p * 32;
                int gr = r0 + r;
                if (gr > n_nodes - 1) gr = n_nodes - 1;
                float4 v = *reinterpret_cast<const float4*>(h + (size_t)gr * NDIM + kc + kk * 4);
                ht_s[(kk * 4 + 0) * 132 + r] = v.x;
                ht_s[(kk * 4 + 1) * 132 + r] = v.y;
                ht_s[(kk * 4 + 2) * 132 + r] = v.z;
                ht_s[(kk * 4 + 3) * 132 + r] = v.w;
            }
        }
        __syncthreads();

        const float4* wt4 = reinterpret_cast<const float4*>(wt_s);
        const float4* ht4 = reinterpret_cast<const float4*>(ht_s);
#pragma unroll
        for (int k = 0; k < 32; ++k) {
            float4 w0 = wt4[k * 32 + ct * 2];
            float4 w1 = wt4[k * 32 + ct * 2 + 1];
            float4 h0 = ht4[k * 33 + rt * 2];
            float4 h1 = ht4[k * 33 + rt * 2 + 1];
            float hs0[4] = {h0.x, h0.y, h0.z, h0.w};
            float hs1[4] = {h1.x, h1.y, h1.z, h1.w};
#pragma unroll
            for (int r = 0; r < 4; ++r) {
                float s = hs0[r];
                acc[r][0].x = fmaf(s, w0.x, acc[r][0].x);
                acc[r][0].y = fmaf(s, w0.y, acc[r][0].y);
                acc[r][0].z = fmaf(s, w0.z, acc[r][0].z);
                acc[r][0].w = fmaf(s, w0.w, acc[r][0].w);
                acc[r][1].x = fmaf(s, w1.x, acc[r][1].x);
                acc[r][1].y = fmaf(s, w1.y, acc[r][1].y);
                acc[r][1].z = fmaf(s, w1.z, acc[r][1].z);
                acc[r][1].w = fmaf(s, w1.w, acc[r][1].w);
            }
#pragma unroll
            for (int r = 0; r < 4; ++r) {
                float s = hs1[r];
                acc[r + 4][0].x = fmaf(s, w0.x, acc[r + 4][0].x);
                acc[r + 4][0].y = fmaf(s, w0.y, acc[r + 4][0].y);
                acc[r + 4][0].z = fmaf(s, w0.z, acc[r + 4][0].z);
                acc[r + 4][0].w = fmaf(s, w0.w, acc[r + 4][0].w);
                acc[r + 4][1].x = fmaf(s, w1.x, acc[r + 4][1].x);
                acc[r + 4][1].y = fmaf(s, w1.y, acc[r + 4][1].y);
                acc[r + 4][1].z = fmaf(s, w1.z, acc[r + 4][1].z);
                acc[r + 4][1].w = fmaf(s, w1.w, acc[r + 4][1].w);
            }
        }
    }

    int c8 = ct * 8;
    float4 bv0 = *reinterpret_cast<const float4*>(bias + c8);
    float4 bv1 = *reinterpret_cast<const float4*>(bias + c8 + 4);
#pragma unroll
    for (int r = 0; r < 8; ++r) {
        int gr = r0 + rt * 8 + r;
        if (gr >= n_nodes) continue;
        float4 o0 = acc[r][0], o1 = acc[r][1];
        o0.x += bv0.x; o0.y += bv0.y; o0.z += bv0.z; o0.w += bv0.w;
        o1.x += bv1.x; o1.y += bv1.y; o1.z += bv1.z; o1.w += bv1.w;
        if (RELU) {
            o0.x = fmaxf(o0.x, 0.f); o0.y = fmaxf(o0.y, 0.f);
            o0.z = fmaxf(o0.z, 0.f); o0.w = fmaxf(o0.w, 0.f);
            o1.x = fmaxf(o1.x, 0.f); o1.y = fmaxf(o1.y, 0.f);
            o1.z = fmaxf(o1.z, 0.f); o1.w = fmaxf(o1.w, 0.f);
        }
        if (OUTBF) {
            uint4 pk;
            pk.x = (unsigned)f2bf_rne(o0.x) | ((unsigned)f2bf_rne(o0.y) << 16);
            pk.y = (unsigned)f2bf_rne(o0.z) | ((unsigned)f2bf_rne(o0.w) << 16);
            pk.z = (unsigned)f2bf_rne(o1.x) | ((unsigned)f2bf_rne(o1.y) << 16);
            pk.w = (unsigned)f2bf_rne(o1.z) | ((unsigned)f2bf_rne(o1.w) << 16);
            *reinterpret_cast<uint4*>(out_bf + (size_t)gr * NDIM + c8) = pk;
        } else {
            float* op = out + (size_t)gr * NDIM + c8;
            *reinterpret_cast<float4*>(op)     = o0;
            *reinterpret_cast<float4*>(op + 4) = o1;
        }
    }
}

extern "C" void kernel_launch(void* const* d_in, const int* in_sizes, int n_in,
                              void* d_out, int out_size, void* d_ws, size_t ws_size,
                              hipStream_t stream) {
    const float* features = (const float*)d_in[0];
    const int*   src      = (const int*)d_in[1];
    const int*   dst      = (const int*)d_in[2];
    const float* W1       = (const float*)d_in[3];
    const float* b1       = (const float*)d_in[4];
    const float* W2       = (const float*)d_in[5];
    const float* b2       = (const float*)d_in[6];
    float* out = (float*)d_out;

    int n_nodes = in_sizes[0] / NDIM;   // 50000
    int n_edges = in_sizes[1];          // 800000
    int nbk = (n_nodes + 255) >> 8;     // 196 buckets

    // ws layout
    float* hneigh = (float*)d_ws;                          // N*128 f32
    float* WT1    = hneigh + (size_t)n_nodes * NDIM;       // 16384
    float* WT2    = WT1 + NDIM * NDIM;                     // 16384
    int*   counts     = (int*)(WT2 + NDIM * NDIM);         // N
    int*   row_ptr    = counts + n_nodes;                  // N+1
    int*   cursor     = row_ptr + n_nodes + 1;             // N
    int*   block_sums = cursor + n_nodes;                  // 128
    int*   col        = block_sums + 128;                  // E
    unsigned short* feat_bf = (unsigned short*)(col + n_edges);   // N*128 bf16
    int*   bcur  = (int*)(feat_bf + (size_t)n_nodes * NDIM);      // nbk*16
    int*   bdata = bcur + (size_t)nbk * 16;                       // E
    size_t needed_bf = ((size_t)n_nodes * NDIM + 2 * NDIM * NDIM) * sizeof(float)
                     + ((size_t)3 * n_nodes + 1 + 128 + n_edges) * sizeof(int)
                     + (size_t)n_nodes * NDIM * sizeof(unsigned short);
    size_t needed_all = needed_bf + ((size_t)nbk * 16 + n_edges) * sizeof(int);

    unsigned short* h1_bf = (unsigned short*)d_out;   // h1 bf16 in d_out storage

    transpose_w2<<<128, 256, 0, stream>>>(W1, W2, WT1, WT2);

    // ---- row_ptr build ----
    hipMemsetAsync(counts, 0, (size_t)n_nodes * sizeof(int), stream);
    int eb = (n_edges + 255) / 256;
    hist_dst<<<eb, 256, 0, stream>>>(dst, counts, n_edges);
    int nb = (n_nodes + SCAN_BS - 1) / SCAN_BS;            // 98
    scan_local<<<nb, SCAN_BS, 0, stream>>>(counts, row_ptr, block_sums, n_nodes);
    scan_blocksums<<<1, 128, 0, stream>>>(block_sums, nb);
    scan_apply<<<nb, SCAN_BS, 0, stream>>>(row_ptr, cursor, block_sums, n_nodes, nb);

    // ---- col fill ----
    bool fast_fill = (ws_size >= needed_all) && (n_nodes <= 65536);
    if (fast_fill) {
        init_bcur<<<(nbk + 255) / 256, 256, 0, stream>>>(row_ptr, bcur, nbk);
        partition_edges<<<eb, 256, 0, stream>>>(src, dst, bcur, bdata, n_edges);
        bucket_sort<<<nbk, 256, 0, stream>>>(row_ptr, bdata, col, n_nodes);
    } else {
        fill_csr<<<eb, 256, 0, stream>>>(src, dst, cursor, col, n_edges);
    }

    int ab = (int)(((long)n_nodes * 64 + 255) / 256);   // one wave per node
    int lb = (n_nodes + 127) / 128;                     // 128 rows per block

    if (ws_size >= needed_bf) {
        // ---- bf16 gather path ----
        int n8 = n_nodes * (NDIM / 8);
        convert_bf<<<(n8 + 255) / 256, 256, 0, stream>>>(features, feat_bf, n8);

        aggregate_bf<<<ab, 256, 0, stream>>>((const uint4*)feat_bf, row_ptr, col, hneigh, n_nodes);
        linear_lds<true, true><<<lb, 256, 0, stream>>>(hneigh, WT1, b1, nullptr, h1_bf, n_nodes);
        aggregate_bf<<<ab, 256, 0, stream>>>((const uint4*)h1_bf, row_ptr, col, hneigh, n_nodes);
        linear_lds<false, false><<<lb, 256, 0, stream>>>(hneigh, WT2, b2, out, nullptr, n_nodes);
    } else {
        // ---- f32 fallback ----
        aggregate<<<ab, 256, 0, stream>>>(features, row_ptr, col, hneigh, n_nodes);
        linear_lds<true, false><<<lb, 256, 0, stream>>>(hneigh, WT1, b1, out, nullptr, n_nodes);
        aggregate<<<ab, 256, 0, stream>>>(out, row_ptr, col, hneigh, n_nodes);
        linear_lds<false, false><<<lb, 256, 0, stream>>>(hneigh, WT2, b2, out, nullptr, n_nodes);
    }
}

// Round 8
// 245.221 us; speedup vs baseline: 1.1314x; 1.1314x over previous
//
#include <hip/hip_runtime.h>

// MPNN: h1 = relu(segsum(feat[src] -> dst) @ W1^T + b1)
//       out = segsum(h1[src] -> dst) @ W2^T + b2
// N=50000, E=800000, d=128.
//
// Round 7->8: 196-bucket partition (83us, same-line atomic serialization
// ~4100 RMW/line) -> 1563 buckets of 32 nodes (~512/line). bucket_sort now
// also builds row_ptr from LDS local histograms, eliminating hist_dst +
// scan_local/apply entirely. CSR fill: memset(100KB) -> count -> scan(1blk)
// -> partition -> bucket_sort_rp.

#define NDIM 128
#define SCAN_BS 512
#define BKT_SHIFT 5                 // 32 nodes per bucket
#define BKT_NODES (1 << BKT_SHIFT)

__device__ inline unsigned short f2bf_rne(float x) {
    unsigned u = __float_as_uint(x);
    unsigned lsb = (u >> 16) & 1u;
    u += 0x7fffu + lsb;
    return (unsigned short)(u >> 16);
}

// ---------------- weight transpose ----------------
__global__ void transpose_w2(const float* __restrict__ W1, const float* __restrict__ W2,
                             float* __restrict__ WT1, float* __restrict__ WT2) {
    int tid = blockIdx.x * 256 + threadIdx.x;   // 32768 threads
    int which = tid >> 14;
    int t = tid & 16383;
    int o = t >> 7;
    int i = t & 127;
    if (which == 0) WT1[i * NDIM + o] = W1[o * NDIM + i];
    else            WT2[i * NDIM + o] = W2[o * NDIM + i];
}

// ---------------- f32 -> bf16 table conversion ----------------
__global__ void convert_bf(const float* __restrict__ in, unsigned short* __restrict__ out,
                           int n8) {
    int i = blockIdx.x * blockDim.x + threadIdx.x;
    if (i >= n8) return;
    const float4* p = reinterpret_cast<const float4*>(in + (size_t)i * 8);
    float4 a = p[0], b = p[1];
    uint4 pk;
    pk.x = (unsigned)f2bf_rne(a.x) | ((unsigned)f2bf_rne(a.y) << 16);
    pk.y = (unsigned)f2bf_rne(a.z) | ((unsigned)f2bf_rne(a.w) << 16);
    pk.z = (unsigned)f2bf_rne(b.x) | ((unsigned)f2bf_rne(b.y) << 16);
    pk.w = (unsigned)f2bf_rne(b.z) | ((unsigned)f2bf_rne(b.w) << 16);
    *reinterpret_cast<uint4*>(out + (size_t)i * 8) = pk;
}

// ================= fast CSR build (2-level counting sort) =================
// bucket b = dst >> 5 (32 nodes). bcur padded to 64B/bucket.

__global__ void count_buckets(const int* __restrict__ dst, int* __restrict__ bcur,
                              int n_edges) {
    int i = blockIdx.x * blockDim.x + threadIdx.x;
    if (i < n_edges) atomicAdd(&bcur[(dst[i] >> BKT_SHIFT) * 16], 1);
}

// single block: exclusive scan of bucket counts -> bbase[b], bcur[b*16]=base
__global__ __launch_bounds__(1024) void scan_buckets(int* __restrict__ bcur,
                                                     int* __restrict__ bbase, int nbk) {
    __shared__ int part[1024];
    int t = threadIdx.x;
    int chunk = (nbk + 1023) / 1024;
    int beg = t * chunk;
    int end = min(beg + chunk, nbk);
    int s = 0;
    for (int i = beg; i < end; ++i) s += bcur[i * 16];
    part[t] = s;
    __syncthreads();
    for (int off = 1; off < 1024; off <<= 1) {
        int v = (t >= off) ? part[t - off] : 0;
        __syncthreads();
        part[t] += v;
        __syncthreads();
    }
    int run = (t == 0) ? 0 : part[t - 1];
    for (int i = beg; i < end; ++i) {
        int c = bcur[i * 16];
        bbase[i] = run;
        bcur[i * 16] = run;
        run += c;
    }
}

__global__ void partition_edges(const int* __restrict__ src, const int* __restrict__ dst,
                                int* __restrict__ bcur, int* __restrict__ bdata, int n_edges) {
    int i = blockIdx.x * blockDim.x + threadIdx.x;
    if (i >= n_edges) return;
    int d = dst[i];
    int s = src[i];
    int b = d >> BKT_SHIFT;
    int pos = atomicAdd(&bcur[b * 16], 1);
    bdata[pos] = s | ((d & (BKT_NODES - 1)) << 16);   // requires n_nodes <= 65536
}

// one block per bucket: LDS histogram -> row_ptr slice + sorted col.
__global__ __launch_bounds__(256) void bucket_sort_rp(const int* __restrict__ bbase,
                                                      const int* __restrict__ bdata,
                                                      int* __restrict__ row_ptr,
                                                      int* __restrict__ col,
                                                      int n_nodes, int n_edges, int nbk) {
    __shared__ int lcnt[BKT_NODES];
    __shared__ int lcur[BKT_NODES];
    int b = blockIdx.x;
    int t = threadIdx.x;
    int node0 = b << BKT_SHIFT;
    int nloc = min(BKT_NODES, n_nodes - node0);
    int base = bbase[b];
    int next = (b + 1 < nbk) ? bbase[b + 1] : n_edges;
    int cnt = next - base;
    if (t < BKT_NODES) lcnt[t] = 0;
    __syncthreads();
    for (int i = t; i < cnt; i += 256) {
        atomicAdd(&lcnt[bdata[base + i] >> 16], 1);
    }
    __syncthreads();
    if (t == 0) {
        int run = 0;
#pragma unroll
        for (int j = 0; j < BKT_NODES; ++j) { lcur[j] = run; run += lcnt[j]; }
    }
    __syncthreads();
    if (t < nloc) row_ptr[node0 + t] = base + lcur[t];
    if (b == nbk - 1 && t == 0) row_ptr[n_nodes] = n_edges;
    __syncthreads();
    for (int i = t; i < cnt; i += 256) {
        int pack = bdata[base + i];
        int pos = atomicAdd(&lcur[pack >> 16], 1);
        col[base + pos] = pack & 0xFFFF;
    }
}

// ================= fallback CSR build (round-6 pipeline) =================
__global__ void hist_dst(const int* __restrict__ dst, int* __restrict__ counts, int n_edges) {
    int i = blockIdx.x * blockDim.x + threadIdx.x;
    if (i < n_edges) atomicAdd(&counts[dst[i]], 1);
}

__global__ __launch_bounds__(SCAN_BS) void scan_local(const int* __restrict__ counts,
                                                      int* __restrict__ row_ptr,
                                                      int* __restrict__ block_sums, int n) {
    __shared__ int sh[SCAN_BS];
    int t = threadIdx.x;
    int i = blockIdx.x * SCAN_BS + t;
    int v = (i < n) ? counts[i] : 0;
    sh[t] = v;
    __syncthreads();
    for (int off = 1; off < SCAN_BS; off <<= 1) {
        int u = (t >= off) ? sh[t - off] : 0;
        __syncthreads();
        sh[t] += u;
        __syncthreads();
    }
    if (i < n) row_ptr[i] = sh[t] - v;
    if (t == SCAN_BS - 1) block_sums[blockIdx.x] = sh[t];
}

__global__ __launch_bounds__(128) void scan_blocksums(int* __restrict__ block_sums, int nb) {
    __shared__ int sh[128];
    int t = threadIdx.x;
    sh[t] = (t < nb) ? block_sums[t] : 0;
    __syncthreads();
    for (int off = 1; off < 128; off <<= 1) {
        int u = (t >= off) ? sh[t - off] : 0;
        __syncthreads();
        sh[t] += u;
        __syncthreads();
    }
    if (t < nb) block_sums[t] = sh[t];
}

__global__ __launch_bounds__(SCAN_BS) void scan_apply(int* __restrict__ row_ptr,
                                                      int* __restrict__ cursor,
                                                      const int* __restrict__ block_sums,
                                                      int n, int nb) {
    int b = blockIdx.x;
    int i = b * SCAN_BS + threadIdx.x;
    int add = (b == 0) ? 0 : block_sums[b - 1];
    if (i < n) {
        int r = row_ptr[i] + add;
        row_ptr[i] = r;
        cursor[i]  = r;
    }
    if (i == 0) row_ptr[n] = block_sums[nb - 1];
}

__global__ void fill_csr(const int* __restrict__ src, const int* __restrict__ dst,
                         int* __restrict__ cursor, int* __restrict__ col, int n_edges) {
    int i = blockIdx.x * blockDim.x + threadIdx.x;
    if (i < n_edges) {
        int pos = atomicAdd(&cursor[dst[i]], 1);
        col[pos] = src[i];
    }
}

// ---------------- bf16 gather-side segment sum ----------------
__global__ void aggregate_bf(const uint4* __restrict__ feat_bf,   // [N][16] uint4
                             const int* __restrict__ row_ptr,
                             const int* __restrict__ col,
                             float* __restrict__ out, int n_nodes) {
    int wid  = (blockIdx.x * blockDim.x + threadIdx.x) >> 6;
    int lane = threadIdx.x & 63;
    if (wid >= n_nodes) return;
    int sub = lane >> 4;            // edge slot 0..3
    int d   = lane & 15;            // 16B chunk within row
    int beg = row_ptr[wid];
    int end = row_ptr[wid + 1];
    float acc[8] = {0.f,0.f,0.f,0.f,0.f,0.f,0.f,0.f};

    int e = beg + sub;
    for (; e + 4 < end; e += 8) {
        int s0 = col[e];
        int s1 = col[e + 4];
        uint4 a = feat_bf[(size_t)s0 * 16 + d];
        uint4 b = feat_bf[(size_t)s1 * 16 + d];
        unsigned aw[4] = {a.x, a.y, a.z, a.w};
        unsigned bw[4] = {b.x, b.y, b.z, b.w};
#pragma unroll
        for (int j = 0; j < 4; ++j) {
            acc[2*j]   += __uint_as_float(aw[j] << 16);
            acc[2*j+1] += __uint_as_float(aw[j] & 0xFFFF0000u);
            acc[2*j]   += __uint_as_float(bw[j] << 16);
            acc[2*j+1] += __uint_as_float(bw[j] & 0xFFFF0000u);
        }
    }
    for (; e < end; e += 4) {
        int s0 = col[e];
        uint4 a = feat_bf[(size_t)s0 * 16 + d];
        unsigned aw[4] = {a.x, a.y, a.z, a.w};
#pragma unroll
        for (int j = 0; j < 4; ++j) {
            acc[2*j]   += __uint_as_float(aw[j] << 16);
            acc[2*j+1] += __uint_as_float(aw[j] & 0xFFFF0000u);
        }
    }
#pragma unroll
    for (int j = 0; j < 8; ++j) {
        acc[j] += __shfl_xor(acc[j], 16, 64);
        acc[j] += __shfl_xor(acc[j], 32, 64);
    }
    if (sub == 0) {
        float4 r0 = make_float4(acc[0], acc[1], acc[2], acc[3]);
        float4 r1 = make_float4(acc[4], acc[5], acc[6], acc[7]);
        float* op = out + (size_t)wid * NDIM + d * 8;
        *reinterpret_cast<float4*>(op)     = r0;
        *reinterpret_cast<float4*>(op + 4) = r1;
    }
}

// ---------------- f32 gather (fallback path) ----------------
__global__ void aggregate(const float* __restrict__ feat,
                          const int* __restrict__ row_ptr,
                          const int* __restrict__ col,
                          float* __restrict__ out, int n_nodes) {
    int wid  = (blockIdx.x * blockDim.x + threadIdx.x) >> 6;
    int lane = threadIdx.x & 63;
    if (wid >= n_nodes) return;
    int half = lane >> 5;
    int d4   = (lane & 31) << 2;
    int beg = row_ptr[wid];
    int end = row_ptr[wid + 1];
    float ax = 0.f, ay = 0.f, az = 0.f, aw = 0.f;
    float bx = 0.f, by = 0.f, bz = 0.f, bw = 0.f;
    int k = beg + half;
    for (; k + 2 < end; k += 4) {
        int s0 = col[k];
        int s1 = col[k + 2];
        float4 v0 = *reinterpret_cast<const float4*>(feat + (size_t)s0 * NDIM + d4);
        float4 v1 = *reinterpret_cast<const float4*>(feat + (size_t)s1 * NDIM + d4);
        ax += v0.x; ay += v0.y; az += v0.z; aw += v0.w;
        bx += v1.x; by += v1.y; bz += v1.z; bw += v1.w;
    }
    if (k < end) {
        int s0 = col[k];
        float4 v0 = *reinterpret_cast<const float4*>(feat + (size_t)s0 * NDIM + d4);
        ax += v0.x; ay += v0.y; az += v0.z; aw += v0.w;
    }
    ax += bx; ay += by; az += bz; aw += bw;
    ax += __shfl(ax, lane ^ 32, 64);
    ay += __shfl(ay, lane ^ 32, 64);
    az += __shfl(az, lane ^ 32, 64);
    aw += __shfl(aw, lane ^ 32, 64);
    if (half == 0) {
        float4 r; r.x = ax; r.y = ay; r.z = az; r.w = aw;
        *reinterpret_cast<float4*>(out + (size_t)wid * NDIM + d4) = r;
    }
}

// ---------------- W-stationary LDS-tiled linear ----------------
template <bool RELU, bool OUTBF>
__global__ __launch_bounds__(256) void linear_lds(const float* __restrict__ h,
                                                  const float* __restrict__ WT,
                                                  const float* __restrict__ bias,
                                                  float* __restrict__ out,
                                                  unsigned short* __restrict__ out_bf,
                                                  int n_nodes) {
    __shared__ float wt_s[32 * 128];        // [k][c]
    __shared__ float ht_s[32 * 132];        // [k][r], stride 132
    int t  = threadIdx.x;
    int ct = t & 15;
    int rt = t >> 4;
    int r0 = blockIdx.x * 128;

    float4 acc[8][2];
#pragma unroll
    for (int r = 0; r < 8; ++r) {
        acc[r][0] = make_float4(0.f, 0.f, 0.f, 0.f);
        acc[r][1] = make_float4(0.f, 0.f, 0.f, 0.f);
    }

    for (int kc = 0; kc < NDIM; kc += 32) {
        __syncthreads();
        {
            const float4* wsrc = reinterpret_cast<const float4*>(WT + kc * NDIM);
            float4* wdst = reinterpret_cast<float4*>(wt_s);
#pragma unroll
            for (int i = 0; i < 4; ++i) wdst[t + 256 * i] = wsrc[t + 256 * i];
        }
        {
            int rr = t >> 3;            // 0..31
            int kk = t & 7;             // 0..7
#pragma unroll
            for (int p = 0; p < 4; ++p) {
                int r = rr + p * 32;
                int gr = r0 + r;
                if (gr > n_nodes - 1) gr = n_nodes - 1;
                float4 v = *reinterpret_cast<const float4*>(h + (size_t)gr * NDIM + kc + kk * 4);
                ht_s[(kk * 4 + 0) * 132 + r] = v.x;
                ht_s[(kk * 4 + 1) * 132 + r] = v.y;
                ht_s[(kk * 4 + 2) * 132 + r] = v.z;
                ht_s[(kk * 4 + 3) * 132 + r] = v.w;
            }
        }
        __syncthreads();

        const float4* wt4 = reinterpret_cast<const float4*>(wt_s);
        const float4* ht4 = reinterpret_cast<const float4*>(ht_s);
#pragma unroll
        for (int k = 0; k < 32; ++k) {
            float4 w0 = wt4[k * 32 + ct * 2];
            float4 w1 = wt4[k * 32 + ct * 2 + 1];
            float4 h0 = ht4[k * 33 + rt * 2];
            float4 h1 = ht4[k * 33 + rt * 2 + 1];
            float hs0[4] = {h0.x, h0.y, h0.z, h0.w};
            float hs1[4] = {h1.x, h1.y, h1.z, h1.w};
#pragma unroll
            for (int r = 0; r < 4; ++r) {
                float s = hs0[r];
                acc[r][0].x = fmaf(s, w0.x, acc[r][0].x);
                acc[r][0].y = fmaf(s, w0.y, acc[r][0].y);
                acc[r][0].z = fmaf(s, w0.z, acc[r][0].z);
                acc[r][0].w = fmaf(s, w0.w, acc[r][0].w);
                acc[r][1].x = fmaf(s, w1.x, acc[r][1].x);
                acc[r][1].y = fmaf(s, w1.y, acc[r][1].y);
                acc[r][1].z = fmaf(s, w1.z, acc[r][1].z);
                acc[r][1].w = fmaf(s, w1.w, acc[r][1].w);
            }
#pragma unroll
            for (int r = 0; r < 4; ++r) {
                float s = hs1[r];
                acc[r + 4][0].x = fmaf(s, w0.x, acc[r + 4][0].x);
                acc[r + 4][0].y = fmaf(s, w0.y, acc[r + 4][0].y);
                acc[r + 4][0].z = fmaf(s, w0.z, acc[r + 4][0].z);
                acc[r + 4][0].w = fmaf(s, w0.w, acc[r + 4][0].w);
                acc[r + 4][1].x = fmaf(s, w1.x, acc[r + 4][1].x);
                acc[r + 4][1].y = fmaf(s, w1.y, acc[r + 4][1].y);
                acc[r + 4][1].z = fmaf(s, w1.z, acc[r + 4][1].z);
                acc[r + 4][1].w = fmaf(s, w1.w, acc[r + 4][1].w);
            }
        }
    }

    int c8 = ct * 8;
    float4 bv0 = *reinterpret_cast<const float4*>(bias + c8);
    float4 bv1 = *reinterpret_cast<const float4*>(bias + c8 + 4);
#pragma unroll
    for (int r = 0; r < 8; ++r) {
        int gr = r0 + rt * 8 + r;
        if (gr >= n_nodes) continue;
        float4 o0 = acc[r][0], o1 = acc[r][1];
        o0.x += bv0.x; o0.y += bv0.y; o0.z += bv0.z; o0.w += bv0.w;
        o1.x += bv1.x; o1.y += bv1.y; o1.z += bv1.z; o1.w += bv1.w;
        if (RELU) {
            o0.x = fmaxf(o0.x, 0.f); o0.y = fmaxf(o0.y, 0.f);
            o0.z = fmaxf(o0.z, 0.f); o0.w = fmaxf(o0.w, 0.f);
            o1.x = fmaxf(o1.x, 0.f); o1.y = fmaxf(o1.y, 0.f);
            o1.z = fmaxf(o1.z, 0.f); o1.w = fmaxf(o1.w, 0.f);
        }
        if (OUTBF) {
            uint4 pk;
            pk.x = (unsigned)f2bf_rne(o0.x) | ((unsigned)f2bf_rne(o0.y) << 16);
            pk.y = (unsigned)f2bf_rne(o0.z) | ((unsigned)f2bf_rne(o0.w) << 16);
            pk.z = (unsigned)f2bf_rne(o1.x) | ((unsigned)f2bf_rne(o1.y) << 16);
            pk.w = (unsigned)f2bf_rne(o1.z) | ((unsigned)f2bf_rne(o1.w) << 16);
            *reinterpret_cast<uint4*>(out_bf + (size_t)gr * NDIM + c8) = pk;
        } else {
            float* op = out + (size_t)gr * NDIM + c8;
            *reinterpret_cast<float4*>(op)     = o0;
            *reinterpret_cast<float4*>(op + 4) = o1;
        }
    }
}

extern "C" void kernel_launch(void* const* d_in, const int* in_sizes, int n_in,
                              void* d_out, int out_size, void* d_ws, size_t ws_size,
                              hipStream_t stream) {
    const float* features = (const float*)d_in[0];
    const int*   src      = (const int*)d_in[1];
    const int*   dst      = (const int*)d_in[2];
    const float* W1       = (const float*)d_in[3];
    const float* b1       = (const float*)d_in[4];
    const float* W2       = (const float*)d_in[5];
    const float* b2       = (const float*)d_in[6];
    float* out = (float*)d_out;

    int n_nodes = in_sizes[0] / NDIM;   // 50000
    int n_edges = in_sizes[1];          // 800000
    int nbk = (n_nodes + BKT_NODES - 1) >> BKT_SHIFT;   // 1563 buckets

    // ws layout
    float* hneigh = (float*)d_ws;                          // N*128 f32
    float* WT1    = hneigh + (size_t)n_nodes * NDIM;       // 16384
    float* WT2    = WT1 + NDIM * NDIM;                     // 16384
    int*   counts     = (int*)(WT2 + NDIM * NDIM);         // N (fallback)
    int*   row_ptr    = counts + n_nodes;                  // N+1
    int*   cursor     = row_ptr + n_nodes + 1;             // N (fallback)
    int*   block_sums = cursor + n_nodes;                  // 128 (fallback)
    int*   col        = block_sums + 128;                  // E
    unsigned short* feat_bf = (unsigned short*)(col + n_edges);   // N*128 bf16
    int*   bcur  = (int*)(feat_bf + (size_t)n_nodes * NDIM);      // nbk*16 (padded)
    int*   bdata = bcur + (size_t)nbk * 16;                       // E
    int*   bbase = bdata + n_edges;                               // nbk

    size_t needed_bf = ((size_t)n_nodes * NDIM + 2 * NDIM * NDIM) * sizeof(float)
                     + ((size_t)3 * n_nodes + 1 + 128 + n_edges) * sizeof(int)
                     + (size_t)n_nodes * NDIM * sizeof(unsigned short);
    size_t needed_all = needed_bf + ((size_t)nbk * 17 + n_edges) * sizeof(int);

    unsigned short* h1_bf = (unsigned short*)d_out;   // h1 bf16 in d_out storage

    transpose_w2<<<128, 256, 0, stream>>>(W1, W2, WT1, WT2);

    int eb = (n_edges + 255) / 256;
    bool fast_fill = (ws_size >= needed_all) && (n_nodes <= 65536);

    if (fast_fill) {
        // ---- 2-level counting sort: builds row_ptr AND col ----
        hipMemsetAsync(bcur, 0, (size_t)nbk * 16 * sizeof(int), stream);
        count_buckets<<<eb, 256, 0, stream>>>(dst, bcur, n_edges);
        scan_buckets<<<1, 1024, 0, stream>>>(bcur, bbase, nbk);
        partition_edges<<<eb, 256, 0, stream>>>(src, dst, bcur, bdata, n_edges);
        bucket_sort_rp<<<nbk, 256, 0, stream>>>(bbase, bdata, row_ptr, col,
                                                n_nodes, n_edges, nbk);
    } else {
        // ---- fallback: hist + hierarchical scan + direct fill ----
        hipMemsetAsync(counts, 0, (size_t)n_nodes * sizeof(int), stream);
        hist_dst<<<eb, 256, 0, stream>>>(dst, counts, n_edges);
        int nb = (n_nodes + SCAN_BS - 1) / SCAN_BS;
        scan_local<<<nb, SCAN_BS, 0, stream>>>(counts, row_ptr, block_sums, n_nodes);
        scan_blocksums<<<1, 128, 0, stream>>>(block_sums, nb);
        scan_apply<<<nb, SCAN_BS, 0, stream>>>(row_ptr, cursor, block_sums, n_nodes, nb);
        fill_csr<<<eb, 256, 0, stream>>>(src, dst, cursor, col, n_edges);
    }

    int ab = (int)(((long)n_nodes * 64 + 255) / 256);   // one wave per node
    int lb = (n_nodes + 127) / 128;                     // 128 rows per block

    if (ws_size >= needed_bf) {
        // ---- bf16 gather path ----
        int n8 = n_nodes * (NDIM / 8);
        convert_bf<<<(n8 + 255) / 256, 256, 0, stream>>>(features, feat_bf, n8);

        aggregate_bf<<<ab, 256, 0, stream>>>((const uint4*)feat_bf, row_ptr, col, hneigh, n_nodes);
        linear_lds<true, true><<<lb, 256, 0, stream>>>(hneigh, WT1, b1, nullptr, h1_bf, n_nodes);
        aggregate_bf<<<ab, 256, 0, stream>>>((const uint4*)h1_bf, row_ptr, col, hneigh, n_nodes);
        linear_lds<false, false><<<lb, 256, 0, stream>>>(hneigh, WT2, b2, out, nullptr, n_nodes);
    } else {
        // ---- f32 fallback ----
        aggregate<<<ab, 256, 0, stream>>>(features, row_ptr, col, hneigh, n_nodes);
        linear_lds<true, false><<<lb, 256, 0, stream>>>(hneigh, WT1, b1, out, nullptr, n_nodes);
        aggregate<<<ab, 256, 0, stream>>>(out, row_ptr, col, hneigh, n_nodes);
        linear_lds<false, false><<<lb, 256, 0, stream>>>(hneigh, WT2, b2, out, nullptr, n_nodes);
    }
}

// Round 9
// 223.456 us; speedup vs baseline: 1.2415x; 1.0974x over previous
//
#include <hip/hip_runtime.h>

// MPNN: h1 = relu(segsum(feat[src] -> dst) @ W1^T + b1)
//       out = segsum(h1[src] -> dst) @ W2^T + b2
// N=50000, E=800000, d=128.
//
// Round 8->9: per-edge atomic partition (40MB write-allocate, 50us) replaced
// by block-aggregated radix partition: per-tile LDS histogram -> global scan
// of [bucket][tile] table -> LDS-staged sorted tile -> coalesced bdata write.
// No per-edge global atomics anywhere in the CSR build.

#define NDIM 128
#define SCAN_BS 512
#define BKT_SHIFT 8                 // 256 nodes per bucket
#define BKT_NODES 256
#define TILE 4096
#define NBK_MAX 256

__device__ inline unsigned short f2bf_rne(float x) {
    unsigned u = __float_as_uint(x);
    unsigned lsb = (u >> 16) & 1u;
    u += 0x7fffu + lsb;
    return (unsigned short)(u >> 16);
}

// ---------------- weight transpose ----------------
__global__ void transpose_w2(const float* __restrict__ W1, const float* __restrict__ W2,
                             float* __restrict__ WT1, float* __restrict__ WT2) {
    int tid = blockIdx.x * 256 + threadIdx.x;   // 32768 threads
    int which = tid >> 14;
    int t = tid & 16383;
    int o = t >> 7;
    int i = t & 127;
    if (which == 0) WT1[i * NDIM + o] = W1[o * NDIM + i];
    else            WT2[i * NDIM + o] = W2[o * NDIM + i];
}

// ---------------- f32 -> bf16 table conversion ----------------
__global__ void convert_bf(const float* __restrict__ in, unsigned short* __restrict__ out,
                           int n8) {
    int i = blockIdx.x * blockDim.x + threadIdx.x;
    if (i >= n8) return;
    const float4* p = reinterpret_cast<const float4*>(in + (size_t)i * 8);
    float4 a = p[0], b = p[1];
    uint4 pk;
    pk.x = (unsigned)f2bf_rne(a.x) | ((unsigned)f2bf_rne(a.y) << 16);
    pk.y = (unsigned)f2bf_rne(a.z) | ((unsigned)f2bf_rne(a.w) << 16);
    pk.z = (unsigned)f2bf_rne(b.x) | ((unsigned)f2bf_rne(b.y) << 16);
    pk.w = (unsigned)f2bf_rne(b.z) | ((unsigned)f2bf_rne(b.w) << 16);
    *reinterpret_cast<uint4*>(out + (size_t)i * 8) = pk;
}

// ========== fast CSR build: block-aggregated radix partition ==========
// bucket = dst >> 8 (256 nodes). hist_g layout: [bucket][tile].

__global__ __launch_bounds__(256) void tile_hist(const int* __restrict__ dst,
                                                 int* __restrict__ hist_g,
                                                 int n_edges, int ntiles, int nbk) {
    __shared__ int lh[NBK_MAX];
    int tblk = blockIdx.x;
    int t = threadIdx.x;
    for (int i = t; i < nbk; i += 256) lh[i] = 0;
    __syncthreads();
    int e0 = tblk * TILE;
    int e1 = min(e0 + TILE, n_edges);
    for (int e = e0 + t; e < e1; e += 256)
        atomicAdd(&lh[dst[e] >> BKT_SHIFT], 1);
    __syncthreads();
    for (int i = t; i < nbk; i += 256)
        hist_g[i * ntiles + tblk] = lh[i];
}

// single block: exclusive scan (in place) of hist_g[nbk*ntiles]; emit bbase.
__global__ __launch_bounds__(1024) void scan_hist(int* __restrict__ hist_g,
                                                  int* __restrict__ bbase,
                                                  int total, int ntiles, int nbk) {
    __shared__ int part[1024];
    int t = threadIdx.x;
    int chunk = (total + 1023) / 1024;
    int beg = t * chunk;
    int end = min(beg + chunk, total);
    int s = 0;
    for (int i = beg; i < end; ++i) s += hist_g[i];
    part[t] = s;
    __syncthreads();
    for (int off = 1; off < 1024; off <<= 1) {
        int v = (t >= off) ? part[t - off] : 0;
        __syncthreads();
        part[t] += v;
        __syncthreads();
    }
    int run = (t == 0) ? 0 : part[t - 1];
    for (int i = beg; i < end; ++i) {
        int c = hist_g[i];
        hist_g[i] = run;
        run += c;
    }
    __syncthreads();
    for (int b = t; b < nbk; b += 1024) bbase[b] = hist_g[b * ntiles];
}

// re-read tile, sort into LDS, copy out with per-bucket-contiguous writes.
__global__ __launch_bounds__(256) void tile_scatter(const int* __restrict__ src,
                                                    const int* __restrict__ dst,
                                                    const int* __restrict__ hist_g,
                                                    unsigned* __restrict__ bdata,
                                                    int n_edges, int ntiles, int nbk) {
    __shared__ int lcur[NBK_MAX];
    __shared__ int lbase[NBK_MAX];
    __shared__ int gbase[NBK_MAX];
    __shared__ unsigned sorted[TILE];
    int tblk = blockIdx.x;
    int t = threadIdx.x;
    for (int i = t; i < nbk; i += 256) lcur[i] = 0;
    __syncthreads();
    int e0 = tblk * TILE;
    int e1 = min(e0 + TILE, n_edges);
    // pass 1: local count
    for (int e = e0 + t; e < e1; e += 256)
        atomicAdd(&lcur[dst[e] >> BKT_SHIFT], 1);
    __syncthreads();
    // scan local counts (Hillis-Steele over NBK_MAX lanes via LDS)
    if (t == 0) {
        int run = 0;
        for (int b = 0; b < nbk; ++b) { lbase[b] = run; run += lcur[b]; }
    }
    __syncthreads();
    for (int i = t; i < nbk; i += 256) {
        gbase[i] = hist_g[i * ntiles + tblk];
        lcur[i]  = lbase[i];
    }
    __syncthreads();
    // pass 2: scatter into LDS sorted order (re-read, L1/L2-hot)
    for (int e = e0 + t; e < e1; e += 256) {
        int d = dst[e];
        int s = src[e];
        int b = d >> BKT_SHIFT;
        int p = atomicAdd(&lcur[b], 1);
        sorted[p] = (unsigned)(s & 0xFFFF) | ((unsigned)(d & (BKT_NODES - 1)) << 16)
                  | ((unsigned)b << 24);
    }
    __syncthreads();
    int cnt = e1 - e0;
    for (int j = t; j < cnt; j += 256) {
        unsigned pk = sorted[j];
        int b = pk >> 24;
        bdata[gbase[b] + (j - lbase[b])] = pk;
    }
}

// one block per bucket: LDS histogram -> row_ptr slice + sorted col.
__global__ __launch_bounds__(256) void bucket_sort_rp(const int* __restrict__ bbase,
                                                      const unsigned* __restrict__ bdata,
                                                      int* __restrict__ row_ptr,
                                                      int* __restrict__ col,
                                                      int n_nodes, int n_edges, int nbk) {
    __shared__ int lcnt[BKT_NODES];
    __shared__ int lcur[BKT_NODES];
    int b = blockIdx.x;
    int t = threadIdx.x;
    int node0 = b << BKT_SHIFT;
    int nloc = min(BKT_NODES, n_nodes - node0);
    int base = bbase[b];
    int next = (b + 1 < nbk) ? bbase[b + 1] : n_edges;
    int cnt = next - base;
    lcnt[t] = 0;
    __syncthreads();
    for (int i = t; i < cnt; i += 256)
        atomicAdd(&lcnt[(bdata[base + i] >> 16) & 255], 1);
    __syncthreads();
    int v = lcnt[t];
    lcur[t] = v;
    __syncthreads();
    for (int off = 1; off < 256; off <<= 1) {
        int u = (t >= off) ? lcur[t - off] : 0;
        __syncthreads();
        lcur[t] += u;
        __syncthreads();
    }
    int excl = lcur[t] - v;
    __syncthreads();
    lcur[t] = excl;
    if (t < nloc) row_ptr[node0 + t] = base + excl;
    if (b == nbk - 1 && t == 0) row_ptr[n_nodes] = n_edges;
    __syncthreads();
    for (int i = t; i < cnt; i += 256) {
        unsigned pk = bdata[base + i];
        int pos = atomicAdd(&lcur[(pk >> 16) & 255], 1);
        col[base + pos] = pk & 0xFFFF;
    }
}

// ================= fallback CSR build =================
__global__ void hist_dst(const int* __restrict__ dst, int* __restrict__ counts, int n_edges) {
    int i = blockIdx.x * blockDim.x + threadIdx.x;
    if (i < n_edges) atomicAdd(&counts[dst[i]], 1);
}

__global__ __launch_bounds__(SCAN_BS) void scan_local(const int* __restrict__ counts,
                                                      int* __restrict__ row_ptr,
                                                      int* __restrict__ block_sums, int n) {
    __shared__ int sh[SCAN_BS];
    int t = threadIdx.x;
    int i = blockIdx.x * SCAN_BS + t;
    int v = (i < n) ? counts[i] : 0;
    sh[t] = v;
    __syncthreads();
    for (int off = 1; off < SCAN_BS; off <<= 1) {
        int u = (t >= off) ? sh[t - off] : 0;
        __syncthreads();
        sh[t] += u;
        __syncthreads();
    }
    if (i < n) row_ptr[i] = sh[t] - v;
    if (t == SCAN_BS - 1) block_sums[blockIdx.x] = sh[t];
}

__global__ __launch_bounds__(128) void scan_blocksums(int* __restrict__ block_sums, int nb) {
    __shared__ int sh[128];
    int t = threadIdx.x;
    sh[t] = (t < nb) ? block_sums[t] : 0;
    __syncthreads();
    for (int off = 1; off < 128; off <<= 1) {
        int u = (t >= off) ? sh[t - off] : 0;
        __syncthreads();
        sh[t] += u;
        __syncthreads();
    }
    if (t < nb) block_sums[t] = sh[t];
}

__global__ __launch_bounds__(SCAN_BS) void scan_apply(int* __restrict__ row_ptr,
                                                      int* __restrict__ cursor,
                                                      const int* __restrict__ block_sums,
                                                      int n, int nb) {
    int b = blockIdx.x;
    int i = b * SCAN_BS + threadIdx.x;
    int add = (b == 0) ? 0 : block_sums[b - 1];
    if (i < n) {
        int r = row_ptr[i] + add;
        row_ptr[i] = r;
        cursor[i]  = r;
    }
    if (i == 0) row_ptr[n] = block_sums[nb - 1];
}

__global__ void fill_csr(const int* __restrict__ src, const int* __restrict__ dst,
                         int* __restrict__ cursor, int* __restrict__ col, int n_edges) {
    int i = blockIdx.x * blockDim.x + threadIdx.x;
    if (i < n_edges) {
        int pos = atomicAdd(&cursor[dst[i]], 1);
        col[pos] = src[i];
    }
}

// ---------------- bf16 gather-side segment sum ----------------
__global__ void aggregate_bf(const uint4* __restrict__ feat_bf,   // [N][16] uint4
                             const int* __restrict__ row_ptr,
                             const int* __restrict__ col,
                             float* __restrict__ out, int n_nodes) {
    int wid  = (blockIdx.x * blockDim.x + threadIdx.x) >> 6;
    int lane = threadIdx.x & 63;
    if (wid >= n_nodes) return;
    int sub = lane >> 4;            // edge slot 0..3
    int d   = lane & 15;            // 16B chunk within row
    int beg = row_ptr[wid];
    int end = row_ptr[wid + 1];
    float acc[8] = {0.f,0.f,0.f,0.f,0.f,0.f,0.f,0.f};

    int e = beg + sub;
    for (; e + 4 < end; e += 8) {
        int s0 = col[e];
        int s1 = col[e + 4];
        uint4 a = feat_bf[(size_t)s0 * 16 + d];
        uint4 b = feat_bf[(size_t)s1 * 16 + d];
        unsigned aw[4] = {a.x, a.y, a.z, a.w};
        unsigned bw[4] = {b.x, b.y, b.z, b.w};
#pragma unroll
        for (int j = 0; j < 4; ++j) {
            acc[2*j]   += __uint_as_float(aw[j] << 16);
            acc[2*j+1] += __uint_as_float(aw[j] & 0xFFFF0000u);
            acc[2*j]   += __uint_as_float(bw[j] << 16);
            acc[2*j+1] += __uint_as_float(bw[j] & 0xFFFF0000u);
        }
    }
    for (; e < end; e += 4) {
        int s0 = col[e];
        uint4 a = feat_bf[(size_t)s0 * 16 + d];
        unsigned aw[4] = {a.x, a.y, a.z, a.w};
#pragma unroll
        for (int j = 0; j < 4; ++j) {
            acc[2*j]   += __uint_as_float(aw[j] << 16);
            acc[2*j+1] += __uint_as_float(aw[j] & 0xFFFF0000u);
        }
    }
#pragma unroll
    for (int j = 0; j < 8; ++j) {
        acc[j] += __shfl_xor(acc[j], 16, 64);
        acc[j] += __shfl_xor(acc[j], 32, 64);
    }
    if (sub == 0) {
        float4 r0 = make_float4(acc[0], acc[1], acc[2], acc[3]);
        float4 r1 = make_float4(acc[4], acc[5], acc[6], acc[7]);
        float* op = out + (size_t)wid * NDIM + d * 8;
        *reinterpret_cast<float4*>(op)     = r0;
        *reinterpret_cast<float4*>(op + 4) = r1;
    }
}

// ---------------- f32 gather (fallback path) ----------------
__global__ void aggregate(const float* __restrict__ feat,
                          const int* __restrict__ row_ptr,
                          const int* __restrict__ col,
                          float* __restrict__ out, int n_nodes) {
    int wid  = (blockIdx.x * blockDim.x + threadIdx.x) >> 6;
    int lane = threadIdx.x & 63;
    if (wid >= n_nodes) return;
    int half = lane >> 5;
    int d4   = (lane & 31) << 2;
    int beg = row_ptr[wid];
    int end = row_ptr[wid + 1];
    float ax = 0.f, ay = 0.f, az = 0.f, aw = 0.f;
    float bx = 0.f, by = 0.f, bz = 0.f, bw = 0.f;
    int k = beg + half;
    for (; k + 2 < end; k += 4) {
        int s0 = col[k];
        int s1 = col[k + 2];
        float4 v0 = *reinterpret_cast<const float4*>(feat + (size_t)s0 * NDIM + d4);
        float4 v1 = *reinterpret_cast<const float4*>(feat + (size_t)s1 * NDIM + d4);
        ax += v0.x; ay += v0.y; az += v0.z; aw += v0.w;
        bx += v1.x; by += v1.y; bz += v1.z; bw += v1.w;
    }
    if (k < end) {
        int s0 = col[k];
        float4 v0 = *reinterpret_cast<const float4*>(feat + (size_t)s0 * NDIM + d4);
        ax += v0.x; ay += v0.y; az += v0.z; aw += v0.w;
    }
    ax += bx; ay += by; az += bz; aw += bw;
    ax += __shfl(ax, lane ^ 32, 64);
    ay += __shfl(ay, lane ^ 32, 64);
    az += __shfl(az, lane ^ 32, 64);
    aw += __shfl(aw, lane ^ 32, 64);
    if (half == 0) {
        float4 r; r.x = ax; r.y = ay; r.z = az; r.w = aw;
        *reinterpret_cast<float4*>(out + (size_t)wid * NDIM + d4) = r;
    }
}

// ---------------- W-stationary LDS-tiled linear ----------------
template <bool RELU, bool OUTBF>
__global__ __launch_bounds__(256) void linear_lds(const float* __restrict__ h,
                                                  const float* __restrict__ WT,
                                                  const float* __restrict__ bias,
                                                  float* __restrict__ out,
                                                  unsigned short* __restrict__ out_bf,
                                                  int n_nodes) {
    __shared__ float wt_s[32 * 128];        // [k][c]
    __shared__ float ht_s[32 * 132];        // [k][r], stride 132
    int t  = threadIdx.x;
    int ct = t & 15;
    int rt = t >> 4;
    int r0 = blockIdx.x * 128;

    float4 acc[8][2];
#pragma unroll
    for (int r = 0; r < 8; ++r) {
        acc[r][0] = make_float4(0.f, 0.f, 0.f, 0.f);
        acc[r][1] = make_float4(0.f, 0.f, 0.f, 0.f);
    }

    for (int kc = 0; kc < NDIM; kc += 32) {
        __syncthreads();
        {
            const float4* wsrc = reinterpret_cast<const float4*>(WT + kc * NDIM);
            float4* wdst = reinterpret_cast<float4*>(wt_s);
#pragma unroll
            for (int i = 0; i < 4; ++i) wdst[t + 256 * i] = wsrc[t + 256 * i];
        }
        {
            int rr = t >> 3;            // 0..31
            int kk = t & 7;             // 0..7
#pragma unroll
            for (int p = 0; p < 4; ++p) {
                int r = rr + p * 32;
                int gr = r0 + r;
                if (gr > n_nodes - 1) gr = n_nodes - 1;
                float4 v = *reinterpret_cast<const float4*>(h + (size_t)gr * NDIM + kc + kk * 4);
                ht_s[(kk * 4 + 0) * 132 + r] = v.x;
                ht_s[(kk * 4 + 1) * 132 + r] = v.y;
                ht_s[(kk * 4 + 2) * 132 + r] = v.z;
                ht_s[(kk * 4 + 3) * 132 + r] = v.w;
            }
        }
        __syncthreads();

        const float4* wt4 = reinterpret_cast<const float4*>(wt_s);
        const float4* ht4 = reinterpret_cast<const float4*>(ht_s);
#pragma unroll
        for (int k = 0; k < 32; ++k) {
            float4 w0 = wt4[k * 32 + ct * 2];
            float4 w1 = wt4[k * 32 + ct * 2 + 1];
            float4 h0 = ht4[k * 33 + rt * 2];
            float4 h1 = ht4[k * 33 + rt * 2 + 1];
            float hs0[4] = {h0.x, h0.y, h0.z, h0.w};
            float hs1[4] = {h1.x, h1.y, h1.z, h1.w};
#pragma unroll
            for (int r = 0; r < 4; ++r) {
                float s = hs0[r];
                acc[r][0].x = fmaf(s, w0.x, acc[r][0].x);
                acc[r][0].y = fmaf(s, w0.y, acc[r][0].y);
                acc[r][0].z = fmaf(s, w0.z, acc[r][0].z);
                acc[r][0].w = fmaf(s, w0.w, acc[r][0].w);
                acc[r][1].x = fmaf(s, w1.x, acc[r][1].x);
                acc[r][1].y = fmaf(s, w1.y, acc[r][1].y);
                acc[r][1].z = fmaf(s, w1.z, acc[r][1].z);
                acc[r][1].w = fmaf(s, w1.w, acc[r][1].w);
            }
#pragma unroll
            for (int r = 0; r < 4; ++r) {
                float s = hs1[r];
                acc[r + 4][0].x = fmaf(s, w0.x, acc[r + 4][0].x);
                acc[r + 4][0].y = fmaf(s, w0.y, acc[r + 4][0].y);
                acc[r + 4][0].z = fmaf(s, w0.z, acc[r + 4][0].z);
                acc[r + 4][0].w = fmaf(s, w0.w, acc[r + 4][0].w);
                acc[r + 4][1].x = fmaf(s, w1.x, acc[r + 4][1].x);
                acc[r + 4][1].y = fmaf(s, w1.y, acc[r + 4][1].y);
                acc[r + 4][1].z = fmaf(s, w1.z, acc[r + 4][1].z);
                acc[r + 4][1].w = fmaf(s, w1.w, acc[r + 4][1].w);
            }
        }
    }

    int c8 = ct * 8;
    float4 bv0 = *reinterpret_cast<const float4*>(bias + c8);
    float4 bv1 = *reinterpret_cast<const float4*>(bias + c8 + 4);
#pragma unroll
    for (int r = 0; r < 8; ++r) {
        int gr = r0 + rt * 8 + r;
        if (gr >= n_nodes) continue;
        float4 o0 = acc[r][0], o1 = acc[r][1];
        o0.x += bv0.x; o0.y += bv0.y; o0.z += bv0.z; o0.w += bv0.w;
        o1.x += bv1.x; o1.y += bv1.y; o1.z += bv1.z; o1.w += bv1.w;
        if (RELU) {
            o0.x = fmaxf(o0.x, 0.f); o0.y = fmaxf(o0.y, 0.f);
            o0.z = fmaxf(o0.z, 0.f); o0.w = fmaxf(o0.w, 0.f);
            o1.x = fmaxf(o1.x, 0.f); o1.y = fmaxf(o1.y, 0.f);
            o1.z = fmaxf(o1.z, 0.f); o1.w = fmaxf(o1.w, 0.f);
        }
        if (OUTBF) {
            uint4 pk;
            pk.x = (unsigned)f2bf_rne(o0.x) | ((unsigned)f2bf_rne(o0.y) << 16);
            pk.y = (unsigned)f2bf_rne(o0.z) | ((unsigned)f2bf_rne(o0.w) << 16);
            pk.z = (unsigned)f2bf_rne(o1.x) | ((unsigned)f2bf_rne(o1.y) << 16);
            pk.w = (unsigned)f2bf_rne(o1.z) | ((unsigned)f2bf_rne(o1.w) << 16);
            *reinterpret_cast<uint4*>(out_bf + (size_t)gr * NDIM + c8) = pk;
        } else {
            float* op = out + (size_t)gr * NDIM + c8;
            *reinterpret_cast<float4*>(op)     = o0;
            *reinterpret_cast<float4*>(op + 4) = o1;
        }
    }
}

extern "C" void kernel_launch(void* const* d_in, const int* in_sizes, int n_in,
                              void* d_out, int out_size, void* d_ws, size_t ws_size,
                              hipStream_t stream) {
    const float* features = (const float*)d_in[0];
    const int*   src      = (const int*)d_in[1];
    const int*   dst      = (const int*)d_in[2];
    const float* W1       = (const float*)d_in[3];
    const float* b1       = (const float*)d_in[4];
    const float* W2       = (const float*)d_in[5];
    const float* b2       = (const float*)d_in[6];
    float* out = (float*)d_out;

    int n_nodes = in_sizes[0] / NDIM;   // 50000
    int n_edges = in_sizes[1];          // 800000
    int nbk = (n_nodes + BKT_NODES - 1) >> BKT_SHIFT;   // 196
    int ntiles = (n_edges + TILE - 1) / TILE;           // 196

    // ws layout
    float* hneigh = (float*)d_ws;                          // N*128 f32
    float* WT1    = hneigh + (size_t)n_nodes * NDIM;       // 16384
    float* WT2    = WT1 + NDIM * NDIM;                     // 16384
    int*   counts     = (int*)(WT2 + NDIM * NDIM);         // N (fallback)
    int*   row_ptr    = counts + n_nodes;                  // N+1
    int*   cursor     = row_ptr + n_nodes + 1;             // N (fallback)
    int*   block_sums = cursor + n_nodes;                  // 128 (fallback)
    int*   col        = block_sums + 128;                  // E
    unsigned short* feat_bf = (unsigned short*)(col + n_edges);   // N*128 bf16
    int*      hist_g = (int*)(feat_bf + (size_t)n_nodes * NDIM);  // nbk*ntiles
    int*      bbase  = hist_g + (size_t)nbk * ntiles;             // nbk
    unsigned* bdata  = (unsigned*)(bbase + nbk);                  // E

    size_t needed_bf = ((size_t)n_nodes * NDIM + 2 * NDIM * NDIM) * sizeof(float)
                     + ((size_t)3 * n_nodes + 1 + 128 + n_edges) * sizeof(int)
                     + (size_t)n_nodes * NDIM * sizeof(unsigned short);
    size_t needed_all = needed_bf
                      + ((size_t)nbk * ntiles + nbk + n_edges) * sizeof(int);

    unsigned short* h1_bf = (unsigned short*)d_out;   // h1 bf16 in d_out storage

    transpose_w2<<<128, 256, 0, stream>>>(W1, W2, WT1, WT2);

    int eb = (n_edges + 255) / 256;
    bool fast_fill = (ws_size >= needed_all) && (n_nodes <= 65536) && (nbk <= NBK_MAX);

    if (fast_fill) {
        // ---- block-aggregated radix partition: builds row_ptr AND col ----
        tile_hist<<<ntiles, 256, 0, stream>>>(dst, hist_g, n_edges, ntiles, nbk);
        scan_hist<<<1, 1024, 0, stream>>>(hist_g, bbase, nbk * ntiles, ntiles, nbk);
        tile_scatter<<<ntiles, 256, 0, stream>>>(src, dst, hist_g, bdata,
                                                 n_edges, ntiles, nbk);
        bucket_sort_rp<<<nbk, 256, 0, stream>>>(bbase, bdata, row_ptr, col,
                                                n_nodes, n_edges, nbk);
    } else {
        // ---- fallback: hist + hierarchical scan + direct fill ----
        hipMemsetAsync(counts, 0, (size_t)n_nodes * sizeof(int), stream);
        hist_dst<<<eb, 256, 0, stream>>>(dst, counts, n_edges);
        int nb = (n_nodes + SCAN_BS - 1) / SCAN_BS;
        scan_local<<<nb, SCAN_BS, 0, stream>>>(counts, row_ptr, block_sums, n_nodes);
        scan_blocksums<<<1, 128, 0, stream>>>(block_sums, nb);
        scan_apply<<<nb, SCAN_BS, 0, stream>>>(row_ptr, cursor, block_sums, n_nodes, nb);
        fill_csr<<<eb, 256, 0, stream>>>(src, dst, cursor, col, n_edges);
    }

    int ab = (int)(((long)n_nodes * 64 + 255) / 256);   // one wave per node
    int lb = (n_nodes + 127) / 128;                     // 128 rows per block

    if (ws_size >= needed_bf) {
        // ---- bf16 gather path ----
        int n8 = n_nodes * (NDIM / 8);
        convert_bf<<<(n8 + 255) / 256, 256, 0, stream>>>(features, feat_bf, n8);

        aggregate_bf<<<ab, 256, 0, stream>>>((const uint4*)feat_bf, row_ptr, col, hneigh, n_nodes);
        linear_lds<true, true><<<lb, 256, 0, stream>>>(hneigh, WT1, b1, nullptr, h1_bf, n_nodes);
        aggregate_bf<<<ab, 256, 0, stream>>>((const uint4*)h1_bf, row_ptr, col, hneigh, n_nodes);
        linear_lds<false, false><<<lb, 256, 0, stream>>>(hneigh, WT2, b2, out, nullptr, n_nodes);
    } else {
        // ---- f32 fallback ----
        aggregate<<<ab, 256, 0, stream>>>(features, row_ptr, col, hneigh, n_nodes);
        linear_lds<true, false><<<lb, 256, 0, stream>>>(hneigh, WT1, b1, out, nullptr, n_nodes);
        aggregate<<<ab, 256, 0, stream>>>(out, row_ptr, col, hneigh, n_nodes);
        linear_lds<false, false><<<lb, 256, 0, stream>>>(hneigh, WT2, b2, out, nullptr, n_nodes);
    }
}

// Round 10
// 175.763 us; speedup vs baseline: 1.5784x; 1.2713x over previous
//
#include <hip/hip_runtime.h>

// MPNN: h1 = relu(segsum(feat[src] -> dst) @ W1^T + b1)
//       out = segsum(h1[src] -> dst) @ W2^T + b2
// N=50000, E=800000, d=128.
//
// Round 9->10: scan_hist was a single-block serial scan of 38k entries
// (57us, 0.05% occupancy — same bug class as round 4's scan_counts).
// Replaced with hierarchical 3-kernel scan (in-place local scan + block-sum
// scan + apply-with-bbase-extraction).

#define NDIM 128
#define SCAN_BS 512
#define BKT_SHIFT 8                 // 256 nodes per bucket
#define BKT_NODES 256
#define TILE 4096
#define NBK_MAX 256

__device__ inline unsigned short f2bf_rne(float x) {
    unsigned u = __float_as_uint(x);
    unsigned lsb = (u >> 16) & 1u;
    u += 0x7fffu + lsb;
    return (unsigned short)(u >> 16);
}

// ---------------- weight transpose ----------------
__global__ void transpose_w2(const float* __restrict__ W1, const float* __restrict__ W2,
                             float* __restrict__ WT1, float* __restrict__ WT2) {
    int tid = blockIdx.x * 256 + threadIdx.x;   // 32768 threads
    int which = tid >> 14;
    int t = tid & 16383;
    int o = t >> 7;
    int i = t & 127;
    if (which == 0) WT1[i * NDIM + o] = W1[o * NDIM + i];
    else            WT2[i * NDIM + o] = W2[o * NDIM + i];
}

// ---------------- f32 -> bf16 table conversion ----------------
__global__ void convert_bf(const float* __restrict__ in, unsigned short* __restrict__ out,
                           int n8) {
    int i = blockIdx.x * blockDim.x + threadIdx.x;
    if (i >= n8) return;
    const float4* p = reinterpret_cast<const float4*>(in + (size_t)i * 8);
    float4 a = p[0], b = p[1];
    uint4 pk;
    pk.x = (unsigned)f2bf_rne(a.x) | ((unsigned)f2bf_rne(a.y) << 16);
    pk.y = (unsigned)f2bf_rne(a.z) | ((unsigned)f2bf_rne(a.w) << 16);
    pk.z = (unsigned)f2bf_rne(b.x) | ((unsigned)f2bf_rne(b.y) << 16);
    pk.w = (unsigned)f2bf_rne(b.z) | ((unsigned)f2bf_rne(b.w) << 16);
    *reinterpret_cast<uint4*>(out + (size_t)i * 8) = pk;
}

// ========== fast CSR build: block-aggregated radix partition ==========
// bucket = dst >> 8 (256 nodes). hist_g layout: [bucket][tile].

__global__ __launch_bounds__(256) void tile_hist(const int* __restrict__ dst,
                                                 int* __restrict__ hist_g,
                                                 int n_edges, int ntiles, int nbk) {
    __shared__ int lh[NBK_MAX];
    int tblk = blockIdx.x;
    int t = threadIdx.x;
    for (int i = t; i < nbk; i += 256) lh[i] = 0;
    __syncthreads();
    int e0 = tblk * TILE;
    int e1 = min(e0 + TILE, n_edges);
    for (int e = e0 + t; e < e1; e += 256)
        atomicAdd(&lh[dst[e] >> BKT_SHIFT], 1);
    __syncthreads();
    for (int i = t; i < nbk; i += 256)
        hist_g[i * ntiles + tblk] = lh[i];
}

// ---- hierarchical scan of hist_g (in place), extracting bucket bases ----
__global__ __launch_bounds__(SCAN_BS) void scan_g_local(int* g, int* tsums, int n) {
    __shared__ int sh[SCAN_BS];
    int t = threadIdx.x;
    int i = blockIdx.x * SCAN_BS + t;
    int v = (i < n) ? g[i] : 0;
    sh[t] = v;
    __syncthreads();
    for (int off = 1; off < SCAN_BS; off <<= 1) {
        int u = (t >= off) ? sh[t - off] : 0;
        __syncthreads();
        sh[t] += u;
        __syncthreads();
    }
    if (i < n) g[i] = sh[t] - v;               // local exclusive prefix
    if (t == SCAN_BS - 1) tsums[blockIdx.x] = sh[t];
}

__global__ __launch_bounds__(128) void scan_blocksums(int* __restrict__ block_sums, int nb) {
    __shared__ int sh[128];
    int t = threadIdx.x;
    sh[t] = (t < nb) ? block_sums[t] : 0;
    __syncthreads();
    for (int off = 1; off < 128; off <<= 1) {
        int u = (t >= off) ? sh[t - off] : 0;
        __syncthreads();
        sh[t] += u;
        __syncthreads();
    }
    if (t < nb) block_sums[t] = sh[t];
}

__global__ __launch_bounds__(SCAN_BS) void scan_g_apply(int* g, const int* tsums,
                                                        int* bbase, int n,
                                                        int ntiles, int nbk) {
    int b = blockIdx.x;
    int i = b * SCAN_BS + threadIdx.x;
    if (i >= n) return;
    int add = (b == 0) ? 0 : tsums[b - 1];
    int r = g[i] + add;
    g[i] = r;
    if (i % ntiles == 0) {
        int bk = i / ntiles;
        if (bk < nbk) bbase[bk] = r;
    }
}

// re-read tile, sort into LDS, copy out with per-bucket-contiguous writes.
__global__ __launch_bounds__(256) void tile_scatter(const int* __restrict__ src,
                                                    const int* __restrict__ dst,
                                                    const int* __restrict__ hist_g,
                                                    unsigned* __restrict__ bdata,
                                                    int n_edges, int ntiles, int nbk) {
    __shared__ int lcur[NBK_MAX];
    __shared__ int lbase[NBK_MAX];
    __shared__ int gbase[NBK_MAX];
    __shared__ unsigned sorted[TILE];
    int tblk = blockIdx.x;
    int t = threadIdx.x;
    for (int i = t; i < nbk; i += 256) lcur[i] = 0;
    __syncthreads();
    int e0 = tblk * TILE;
    int e1 = min(e0 + TILE, n_edges);
    // pass 1: local count
    for (int e = e0 + t; e < e1; e += 256)
        atomicAdd(&lcur[dst[e] >> BKT_SHIFT], 1);
    __syncthreads();
    if (t == 0) {
        int run = 0;
        for (int b = 0; b < nbk; ++b) { lbase[b] = run; run += lcur[b]; }
    }
    __syncthreads();
    for (int i = t; i < nbk; i += 256) {
        gbase[i] = hist_g[i * ntiles + tblk];
        lcur[i]  = lbase[i];
    }
    __syncthreads();
    // pass 2: scatter into LDS sorted order (re-read, L1/L2-hot)
    for (int e = e0 + t; e < e1; e += 256) {
        int d = dst[e];
        int s = src[e];
        int b = d >> BKT_SHIFT;
        int p = atomicAdd(&lcur[b], 1);
        sorted[p] = (unsigned)(s & 0xFFFF) | ((unsigned)(d & (BKT_NODES - 1)) << 16)
                  | ((unsigned)b << 24);
    }
    __syncthreads();
    int cnt = e1 - e0;
    for (int j = t; j < cnt; j += 256) {
        unsigned pk = sorted[j];
        int b = pk >> 24;
        bdata[gbase[b] + (j - lbase[b])] = pk;
    }
}

// one block per bucket: LDS histogram -> row_ptr slice + sorted col.
__global__ __launch_bounds__(256) void bucket_sort_rp(const int* __restrict__ bbase,
                                                      const unsigned* __restrict__ bdata,
                                                      int* __restrict__ row_ptr,
                                                      int* __restrict__ col,
                                                      int n_nodes, int n_edges, int nbk) {
    __shared__ int lcnt[BKT_NODES];
    __shared__ int lcur[BKT_NODES];
    int b = blockIdx.x;
    int t = threadIdx.x;
    int node0 = b << BKT_SHIFT;
    int nloc = min(BKT_NODES, n_nodes - node0);
    int base = bbase[b];
    int next = (b + 1 < nbk) ? bbase[b + 1] : n_edges;
    int cnt = next - base;
    lcnt[t] = 0;
    __syncthreads();
    for (int i = t; i < cnt; i += 256)
        atomicAdd(&lcnt[(bdata[base + i] >> 16) & 255], 1);
    __syncthreads();
    int v = lcnt[t];
    lcur[t] = v;
    __syncthreads();
    for (int off = 1; off < 256; off <<= 1) {
        int u = (t >= off) ? lcur[t - off] : 0;
        __syncthreads();
        lcur[t] += u;
        __syncthreads();
    }
    int excl = lcur[t] - v;
    __syncthreads();
    lcur[t] = excl;
    if (t < nloc) row_ptr[node0 + t] = base + excl;
    if (b == nbk - 1 && t == 0) row_ptr[n_nodes] = n_edges;
    __syncthreads();
    for (int i = t; i < cnt; i += 256) {
        unsigned pk = bdata[base + i];
        int pos = atomicAdd(&lcur[(pk >> 16) & 255], 1);
        col[base + pos] = pk & 0xFFFF;
    }
}

// ================= fallback CSR build =================
__global__ void hist_dst(const int* __restrict__ dst, int* __restrict__ counts, int n_edges) {
    int i = blockIdx.x * blockDim.x + threadIdx.x;
    if (i < n_edges) atomicAdd(&counts[dst[i]], 1);
}

__global__ __launch_bounds__(SCAN_BS) void scan_local(const int* __restrict__ counts,
                                                      int* __restrict__ row_ptr,
                                                      int* __restrict__ block_sums, int n) {
    __shared__ int sh[SCAN_BS];
    int t = threadIdx.x;
    int i = blockIdx.x * SCAN_BS + t;
    int v = (i < n) ? counts[i] : 0;
    sh[t] = v;
    __syncthreads();
    for (int off = 1; off < SCAN_BS; off <<= 1) {
        int u = (t >= off) ? sh[t - off] : 0;
        __syncthreads();
        sh[t] += u;
        __syncthreads();
    }
    if (i < n) row_ptr[i] = sh[t] - v;
    if (t == SCAN_BS - 1) block_sums[blockIdx.x] = sh[t];
}

__global__ __launch_bounds__(SCAN_BS) void scan_apply(int* __restrict__ row_ptr,
                                                      int* __restrict__ cursor,
                                                      const int* __restrict__ block_sums,
                                                      int n, int nb) {
    int b = blockIdx.x;
    int i = b * SCAN_BS + threadIdx.x;
    int add = (b == 0) ? 0 : block_sums[b - 1];
    if (i < n) {
        int r = row_ptr[i] + add;
        row_ptr[i] = r;
        cursor[i]  = r;
    }
    if (i == 0) row_ptr[n] = block_sums[nb - 1];
}

__global__ void fill_csr(const int* __restrict__ src, const int* __restrict__ dst,
                         int* __restrict__ cursor, int* __restrict__ col, int n_edges) {
    int i = blockIdx.x * blockDim.x + threadIdx.x;
    if (i < n_edges) {
        int pos = atomicAdd(&cursor[dst[i]], 1);
        col[pos] = src[i];
    }
}

// ---------------- bf16 gather-side segment sum ----------------
__global__ void aggregate_bf(const uint4* __restrict__ feat_bf,   // [N][16] uint4
                             const int* __restrict__ row_ptr,
                             const int* __restrict__ col,
                             float* __restrict__ out, int n_nodes) {
    int wid  = (blockIdx.x * blockDim.x + threadIdx.x) >> 6;
    int lane = threadIdx.x & 63;
    if (wid >= n_nodes) return;
    int sub = lane >> 4;            // edge slot 0..3
    int d   = lane & 15;            // 16B chunk within row
    int beg = row_ptr[wid];
    int end = row_ptr[wid + 1];
    float acc[8] = {0.f,0.f,0.f,0.f,0.f,0.f,0.f,0.f};

    int e = beg + sub;
    for (; e + 4 < end; e += 8) {
        int s0 = col[e];
        int s1 = col[e + 4];
        uint4 a = feat_bf[(size_t)s0 * 16 + d];
        uint4 b = feat_bf[(size_t)s1 * 16 + d];
        unsigned aw[4] = {a.x, a.y, a.z, a.w};
        unsigned bw[4] = {b.x, b.y, b.z, b.w};
#pragma unroll
        for (int j = 0; j < 4; ++j) {
            acc[2*j]   += __uint_as_float(aw[j] << 16);
            acc[2*j+1] += __uint_as_float(aw[j] & 0xFFFF0000u);
            acc[2*j]   += __uint_as_float(bw[j] << 16);
            acc[2*j+1] += __uint_as_float(bw[j] & 0xFFFF0000u);
        }
    }
    for (; e < end; e += 4) {
        int s0 = col[e];
        uint4 a = feat_bf[(size_t)s0 * 16 + d];
        unsigned aw[4] = {a.x, a.y, a.z, a.w};
#pragma unroll
        for (int j = 0; j < 4; ++j) {
            acc[2*j]   += __uint_as_float(aw[j] << 16);
            acc[2*j+1] += __uint_as_float(aw[j] & 0xFFFF0000u);
        }
    }
#pragma unroll
    for (int j = 0; j < 8; ++j) {
        acc[j] += __shfl_xor(acc[j], 16, 64);
        acc[j] += __shfl_xor(acc[j], 32, 64);
    }
    if (sub == 0) {
        float4 r0 = make_float4(acc[0], acc[1], acc[2], acc[3]);
        float4 r1 = make_float4(acc[4], acc[5], acc[6], acc[7]);
        float* op = out + (size_t)wid * NDIM + d * 8;
        *reinterpret_cast<float4*>(op)     = r0;
        *reinterpret_cast<float4*>(op + 4) = r1;
    }
}

// ---------------- f32 gather (fallback path) ----------------
__global__ void aggregate(const float* __restrict__ feat,
                          const int* __restrict__ row_ptr,
                          const int* __restrict__ col,
                          float* __restrict__ out, int n_nodes) {
    int wid  = (blockIdx.x * blockDim.x + threadIdx.x) >> 6;
    int lane = threadIdx.x & 63;
    if (wid >= n_nodes) return;
    int half = lane >> 5;
    int d4   = (lane & 31) << 2;
    int beg = row_ptr[wid];
    int end = row_ptr[wid + 1];
    float ax = 0.f, ay = 0.f, az = 0.f, aw = 0.f;
    float bx = 0.f, by = 0.f, bz = 0.f, bw = 0.f;
    int k = beg + half;
    for (; k + 2 < end; k += 4) {
        int s0 = col[k];
        int s1 = col[k + 2];
        float4 v0 = *reinterpret_cast<const float4*>(feat + (size_t)s0 * NDIM + d4);
        float4 v1 = *reinterpret_cast<const float4*>(feat + (size_t)s1 * NDIM + d4);
        ax += v0.x; ay += v0.y; az += v0.z; aw += v0.w;
        bx += v1.x; by += v1.y; bz += v1.z; bw += v1.w;
    }
    if (k < end) {
        int s0 = col[k];
        float4 v0 = *reinterpret_cast<const float4*>(feat + (size_t)s0 * NDIM + d4);
        ax += v0.x; ay += v0.y; az += v0.z; aw += v0.w;
    }
    ax += bx; ay += by; az += bz; aw += bw;
    ax += __shfl(ax, lane ^ 32, 64);
    ay += __shfl(ay, lane ^ 32, 64);
    az += __shfl(az, lane ^ 32, 64);
    aw += __shfl(aw, lane ^ 32, 64);
    if (half == 0) {
        float4 r; r.x = ax; r.y = ay; r.z = az; r.w = aw;
        *reinterpret_cast<float4*>(out + (size_t)wid * NDIM + d4) = r;
    }
}

// ---------------- W-stationary LDS-tiled linear ----------------
template <bool RELU, bool OUTBF>
__global__ __launch_bounds__(256) void linear_lds(const float* __restrict__ h,
                                                  const float* __restrict__ WT,
                                                  const float* __restrict__ bias,
                                                  float* __restrict__ out,
                                                  unsigned short* __restrict__ out_bf,
                                                  int n_nodes) {
    __shared__ float wt_s[32 * 128];        // [k][c]
    __shared__ float ht_s[32 * 132];        // [k][r], stride 132
    int t  = threadIdx.x;
    int ct = t & 15;
    int rt = t >> 4;
    int r0 = blockIdx.x * 128;

    float4 acc[8][2];
#pragma unroll
    for (int r = 0; r < 8; ++r) {
        acc[r][0] = make_float4(0.f, 0.f, 0.f, 0.f);
        acc[r][1] = make_float4(0.f, 0.f, 0.f, 0.f);
    }

    for (int kc = 0; kc < NDIM; kc += 32) {
        __syncthreads();
        {
            const float4* wsrc = reinterpret_cast<const float4*>(WT + kc * NDIM);
            float4* wdst = reinterpret_cast<float4*>(wt_s);
#pragma unroll
            for (int i = 0; i < 4; ++i) wdst[t + 256 * i] = wsrc[t + 256 * i];
        }
        {
            int rr = t >> 3;            // 0..31
            int kk = t & 7;             // 0..7
#pragma unroll
            for (int p = 0; p < 4; ++p) {
                int r = rr + p * 32;
                int gr = r0 + r;
                if (gr > n_nodes - 1) gr = n_nodes - 1;
                float4 v = *reinterpret_cast<const float4*>(h + (size_t)gr * NDIM + kc + kk * 4);
                ht_s[(kk * 4 + 0) * 132 + r] = v.x;
                ht_s[(kk * 4 + 1) * 132 + r] = v.y;
                ht_s[(kk * 4 + 2) * 132 + r] = v.z;
                ht_s[(kk * 4 + 3) * 132 + r] = v.w;
            }
        }
        __syncthreads();

        const float4* wt4 = reinterpret_cast<const float4*>(wt_s);
        const float4* ht4 = reinterpret_cast<const float4*>(ht_s);
#pragma unroll
        for (int k = 0; k < 32; ++k) {
            float4 w0 = wt4[k * 32 + ct * 2];
            float4 w1 = wt4[k * 32 + ct * 2 + 1];
            float4 h0 = ht4[k * 33 + rt * 2];
            float4 h1 = ht4[k * 33 + rt * 2 + 1];
            float hs0[4] = {h0.x, h0.y, h0.z, h0.w};
            float hs1[4] = {h1.x, h1.y, h1.z, h1.w};
#pragma unroll
            for (int r = 0; r < 4; ++r) {
                float s = hs0[r];
                acc[r][0].x = fmaf(s, w0.x, acc[r][0].x);
                acc[r][0].y = fmaf(s, w0.y, acc[r][0].y);
                acc[r][0].z = fmaf(s, w0.z, acc[r][0].z);
                acc[r][0].w = fmaf(s, w0.w, acc[r][0].w);
                acc[r][1].x = fmaf(s, w1.x, acc[r][1].x);
                acc[r][1].y = fmaf(s, w1.y, acc[r][1].y);
                acc[r][1].z = fmaf(s, w1.z, acc[r][1].z);
                acc[r][1].w = fmaf(s, w1.w, acc[r][1].w);
            }
#pragma unroll
            for (int r = 0; r < 4; ++r) {
                float s = hs1[r];
                acc[r + 4][0].x = fmaf(s, w0.x, acc[r + 4][0].x);
                acc[r + 4][0].y = fmaf(s, w0.y, acc[r + 4][0].y);
                acc[r + 4][0].z = fmaf(s, w0.z, acc[r + 4][0].z);
                acc[r + 4][0].w = fmaf(s, w0.w, acc[r + 4][0].w);
                acc[r + 4][1].x = fmaf(s, w1.x, acc[r + 4][1].x);
                acc[r + 4][1].y = fmaf(s, w1.y, acc[r + 4][1].y);
                acc[r + 4][1].z = fmaf(s, w1.z, acc[r + 4][1].z);
                acc[r + 4][1].w = fmaf(s, w1.w, acc[r + 4][1].w);
            }
        }
    }

    int c8 = ct * 8;
    float4 bv0 = *reinterpret_cast<const float4*>(bias + c8);
    float4 bv1 = *reinterpret_cast<const float4*>(bias + c8 + 4);
#pragma unroll
    for (int r = 0; r < 8; ++r) {
        int gr = r0 + rt * 8 + r;
        if (gr >= n_nodes) continue;
        float4 o0 = acc[r][0], o1 = acc[r][1];
        o0.x += bv0.x; o0.y += bv0.y; o0.z += bv0.z; o0.w += bv0.w;
        o1.x += bv1.x; o1.y += bv1.y; o1.z += bv1.z; o1.w += bv1.w;
        if (RELU) {
            o0.x = fmaxf(o0.x, 0.f); o0.y = fmaxf(o0.y, 0.f);
            o0.z = fmaxf(o0.z, 0.f); o0.w = fmaxf(o0.w, 0.f);
            o1.x = fmaxf(o1.x, 0.f); o1.y = fmaxf(o1.y, 0.f);
            o1.z = fmaxf(o1.z, 0.f); o1.w = fmaxf(o1.w, 0.f);
        }
        if (OUTBF) {
            uint4 pk;
            pk.x = (unsigned)f2bf_rne(o0.x) | ((unsigned)f2bf_rne(o0.y) << 16);
            pk.y = (unsigned)f2bf_rne(o0.z) | ((unsigned)f2bf_rne(o0.w) << 16);
            pk.z = (unsigned)f2bf_rne(o1.x) | ((unsigned)f2bf_rne(o1.y) << 16);
            pk.w = (unsigned)f2bf_rne(o1.z) | ((unsigned)f2bf_rne(o1.w) << 16);
            *reinterpret_cast<uint4*>(out_bf + (size_t)gr * NDIM + c8) = pk;
        } else {
            float* op = out + (size_t)gr * NDIM + c8;
            *reinterpret_cast<float4*>(op)     = o0;
            *reinterpret_cast<float4*>(op + 4) = o1;
        }
    }
}

extern "C" void kernel_launch(void* const* d_in, const int* in_sizes, int n_in,
                              void* d_out, int out_size, void* d_ws, size_t ws_size,
                              hipStream_t stream) {
    const float* features = (const float*)d_in[0];
    const int*   src      = (const int*)d_in[1];
    const int*   dst      = (const int*)d_in[2];
    const float* W1       = (const float*)d_in[3];
    const float* b1       = (const float*)d_in[4];
    const float* W2       = (const float*)d_in[5];
    const float* b2       = (const float*)d_in[6];
    float* out = (float*)d_out;

    int n_nodes = in_sizes[0] / NDIM;   // 50000
    int n_edges = in_sizes[1];          // 800000
    int nbk = (n_nodes + BKT_NODES - 1) >> BKT_SHIFT;   // 196
    int ntiles = (n_edges + TILE - 1) / TILE;           // 196

    // ws layout
    float* hneigh = (float*)d_ws;                          // N*128 f32
    float* WT1    = hneigh + (size_t)n_nodes * NDIM;       // 16384
    float* WT2    = WT1 + NDIM * NDIM;                     // 16384
    int*   counts     = (int*)(WT2 + NDIM * NDIM);         // N (fallback)
    int*   row_ptr    = counts + n_nodes;                  // N+1
    int*   cursor     = row_ptr + n_nodes + 1;             // N (fallback)
    int*   block_sums = cursor + n_nodes;                  // 128 (shared w/ scan_g)
    int*   col        = block_sums + 128;                  // E
    unsigned short* feat_bf = (unsigned short*)(col + n_edges);   // N*128 bf16
    int*      hist_g = (int*)(feat_bf + (size_t)n_nodes * NDIM);  // nbk*ntiles
    int*      bbase  = hist_g + (size_t)nbk * ntiles;             // nbk
    unsigned* bdata  = (unsigned*)(bbase + nbk);                  // E

    size_t needed_bf = ((size_t)n_nodes * NDIM + 2 * NDIM * NDIM) * sizeof(float)
                     + ((size_t)3 * n_nodes + 1 + 128 + n_edges) * sizeof(int)
                     + (size_t)n_nodes * NDIM * sizeof(unsigned short);
    size_t needed_all = needed_bf
                      + ((size_t)nbk * ntiles + nbk + n_edges) * sizeof(int);

    unsigned short* h1_bf = (unsigned short*)d_out;   // h1 bf16 in d_out storage

    transpose_w2<<<128, 256, 0, stream>>>(W1, W2, WT1, WT2);

    int eb = (n_edges + 255) / 256;
    int nscan = nbk * ntiles;
    int nsb = (nscan + SCAN_BS - 1) / SCAN_BS;          // 76 blocks
    bool fast_fill = (ws_size >= needed_all) && (n_nodes <= 65536)
                   && (nbk <= NBK_MAX) && (nsb <= 128);

    if (fast_fill) {
        // ---- block-aggregated radix partition: builds row_ptr AND col ----
        tile_hist<<<ntiles, 256, 0, stream>>>(dst, hist_g, n_edges, ntiles, nbk);
        scan_g_local<<<nsb, SCAN_BS, 0, stream>>>(hist_g, block_sums, nscan);
        scan_blocksums<<<1, 128, 0, stream>>>(block_sums, nsb);
        scan_g_apply<<<nsb, SCAN_BS, 0, stream>>>(hist_g, block_sums, bbase,
                                                  nscan, ntiles, nbk);
        tile_scatter<<<ntiles, 256, 0, stream>>>(src, dst, hist_g, bdata,
                                                 n_edges, ntiles, nbk);
        bucket_sort_rp<<<nbk, 256, 0, stream>>>(bbase, bdata, row_ptr, col,
                                                n_nodes, n_edges, nbk);
    } else {
        // ---- fallback: hist + hierarchical scan + direct fill ----
        hipMemsetAsync(counts, 0, (size_t)n_nodes * sizeof(int), stream);
        hist_dst<<<eb, 256, 0, stream>>>(dst, counts, n_edges);
        int nb = (n_nodes + SCAN_BS - 1) / SCAN_BS;
        scan_local<<<nb, SCAN_BS, 0, stream>>>(counts, row_ptr, block_sums, n_nodes);
        scan_blocksums<<<1, 128, 0, stream>>>(block_sums, nb);
        scan_apply<<<nb, SCAN_BS, 0, stream>>>(row_ptr, cursor, block_sums, n_nodes, nb);
        fill_csr<<<eb, 256, 0, stream>>>(src, dst, cursor, col, n_edges);
    }

    int ab = (int)(((long)n_nodes * 64 + 255) / 256);   // one wave per node
    int lb = (n_nodes + 127) / 128;                     // 128 rows per block

    if (ws_size >= needed_bf) {
        // ---- bf16 gather path ----
        int n8 = n_nodes * (NDIM / 8);
        convert_bf<<<(n8 + 255) / 256, 256, 0, stream>>>(features, feat_bf, n8);

        aggregate_bf<<<ab, 256, 0, stream>>>((const uint4*)feat_bf, row_ptr, col, hneigh, n_nodes);
        linear_lds<true, true><<<lb, 256, 0, stream>>>(hneigh, WT1, b1, nullptr, h1_bf, n_nodes);
        aggregate_bf<<<ab, 256, 0, stream>>>((const uint4*)h1_bf, row_ptr, col, hneigh, n_nodes);
        linear_lds<false, false><<<lb, 256, 0, stream>>>(hneigh, WT2, b2, out, nullptr, n_nodes);
    } else {
        // ---- f32 fallback ----
        aggregate<<<ab, 256, 0, stream>>>(features, row_ptr, col, hneigh, n_nodes);
        linear_lds<true, false><<<lb, 256, 0, stream>>>(hneigh, WT1, b1, out, nullptr, n_nodes);
        aggregate<<<ab, 256, 0, stream>>>(out, row_ptr, col, hneigh, n_nodes);
        linear_lds<false, false><<<lb, 256, 0, stream>>>(hneigh, WT2, b2, out, nullptr, n_nodes);
    }
}

// Round 11
// 149.799 us; speedup vs baseline: 1.8520x; 1.1733x over previous
//
#include <hip/hip_runtime.h>

// MPNN: h1 = relu(segsum(feat[src] -> dst) @ W1^T + b1)
//       out = segsum(h1[src] -> dst) @ W2^T + b2
// N=50000, E=800000, d=128.
//
// Round 10->11: linear layers moved from f32 VALU (LDS-tiled, ~32us each) to
// bf16 MFMA (16x16x32), zero-LDS zero-barrier: A frags from bf16 h table,
// B frags from bf16 W (no transpose: mfma computes h @ W^T directly since W
// is [out][in]). aggregate now emits bf16 h_neigh (halves its write traffic
// and the GEMM's read traffic). f32 accumulation throughout.

#define NDIM 128
#define SCAN_BS 512
#define BKT_SHIFT 8                 // 256 nodes per bucket
#define BKT_NODES 256
#define TILE 4096
#define NBK_MAX 256

typedef __attribute__((ext_vector_type(8))) short bf16x8;
typedef __attribute__((ext_vector_type(4))) float f32x4;

__device__ inline unsigned short f2bf_rne(float x) {
    unsigned u = __float_as_uint(x);
    unsigned lsb = (u >> 16) & 1u;
    u += 0x7fffu + lsb;
    return (unsigned short)(u >> 16);
}

__device__ inline unsigned pack_bf2(float lo, float hi) {
    return (unsigned)f2bf_rne(lo) | ((unsigned)f2bf_rne(hi) << 16);
}

// ---------------- f32 -> bf16 conversion: features + W1 + W2 ----------------
// item = 8 floats. [0,n8): features; [n8,n8+2048): W1; [n8+2048,n8+4096): W2.
__global__ void convert_all(const float* __restrict__ feat, const float* __restrict__ W1,
                            const float* __restrict__ W2,
                            unsigned short* __restrict__ feat_bf,
                            unsigned short* __restrict__ w1_bf,
                            unsigned short* __restrict__ w2_bf, int n8) {
    int i = blockIdx.x * blockDim.x + threadIdx.x;
    const float* srcp;
    unsigned short* dstp;
    int j;
    if (i < n8)                { srcp = feat; dstp = feat_bf; j = i; }
    else if (i < n8 + 2048)    { srcp = W1;   dstp = w1_bf;   j = i - n8; }
    else if (i < n8 + 4096)    { srcp = W2;   dstp = w2_bf;   j = i - n8 - 2048; }
    else return;
    const float4* p = reinterpret_cast<const float4*>(srcp + (size_t)j * 8);
    float4 a = p[0], b = p[1];
    uint4 pk;
    pk.x = pack_bf2(a.x, a.y);
    pk.y = pack_bf2(a.z, a.w);
    pk.z = pack_bf2(b.x, b.y);
    pk.w = pack_bf2(b.z, b.w);
    *reinterpret_cast<uint4*>(dstp + (size_t)j * 8) = pk;
}

// ========== fast CSR build: block-aggregated radix partition ==========
__global__ __launch_bounds__(256) void tile_hist(const int* __restrict__ dst,
                                                 int* __restrict__ hist_g,
                                                 int n_edges, int ntiles, int nbk) {
    __shared__ int lh[NBK_MAX];
    int tblk = blockIdx.x;
    int t = threadIdx.x;
    for (int i = t; i < nbk; i += 256) lh[i] = 0;
    __syncthreads();
    int e0 = tblk * TILE;
    int e1 = min(e0 + TILE, n_edges);
    for (int e = e0 + t; e < e1; e += 256)
        atomicAdd(&lh[dst[e] >> BKT_SHIFT], 1);
    __syncthreads();
    for (int i = t; i < nbk; i += 256)
        hist_g[i * ntiles + tblk] = lh[i];
}

__global__ __launch_bounds__(SCAN_BS) void scan_g_local(int* g, int* tsums, int n) {
    __shared__ int sh[SCAN_BS];
    int t = threadIdx.x;
    int i = blockIdx.x * SCAN_BS + t;
    int v = (i < n) ? g[i] : 0;
    sh[t] = v;
    __syncthreads();
    for (int off = 1; off < SCAN_BS; off <<= 1) {
        int u = (t >= off) ? sh[t - off] : 0;
        __syncthreads();
        sh[t] += u;
        __syncthreads();
    }
    if (i < n) g[i] = sh[t] - v;
    if (t == SCAN_BS - 1) tsums[blockIdx.x] = sh[t];
}

__global__ __launch_bounds__(128) void scan_blocksums(int* __restrict__ block_sums, int nb) {
    __shared__ int sh[128];
    int t = threadIdx.x;
    sh[t] = (t < nb) ? block_sums[t] : 0;
    __syncthreads();
    for (int off = 1; off < 128; off <<= 1) {
        int u = (t >= off) ? sh[t - off] : 0;
        __syncthreads();
        sh[t] += u;
        __syncthreads();
    }
    if (t < nb) block_sums[t] = sh[t];
}

__global__ __launch_bounds__(SCAN_BS) void scan_g_apply(int* g, const int* tsums,
                                                        int* bbase, int n,
                                                        int ntiles, int nbk) {
    int b = blockIdx.x;
    int i = b * SCAN_BS + threadIdx.x;
    if (i >= n) return;
    int add = (b == 0) ? 0 : tsums[b - 1];
    int r = g[i] + add;
    g[i] = r;
    if (i % ntiles == 0) {
        int bk = i / ntiles;
        if (bk < nbk) bbase[bk] = r;
    }
}

__global__ __launch_bounds__(256) void tile_scatter(const int* __restrict__ src,
                                                    const int* __restrict__ dst,
                                                    const int* __restrict__ hist_g,
                                                    unsigned* __restrict__ bdata,
                                                    int n_edges, int ntiles, int nbk) {
    __shared__ int lcur[NBK_MAX];
    __shared__ int lbase[NBK_MAX];
    __shared__ int gbase[NBK_MAX];
    __shared__ unsigned sorted[TILE];
    int tblk = blockIdx.x;
    int t = threadIdx.x;
    for (int i = t; i < nbk; i += 256) lcur[i] = 0;
    __syncthreads();
    int e0 = tblk * TILE;
    int e1 = min(e0 + TILE, n_edges);
    for (int e = e0 + t; e < e1; e += 256)
        atomicAdd(&lcur[dst[e] >> BKT_SHIFT], 1);
    __syncthreads();
    if (t == 0) {
        int run = 0;
        for (int b = 0; b < nbk; ++b) { lbase[b] = run; run += lcur[b]; }
    }
    __syncthreads();
    for (int i = t; i < nbk; i += 256) {
        gbase[i] = hist_g[i * ntiles + tblk];
        lcur[i]  = lbase[i];
    }
    __syncthreads();
    for (int e = e0 + t; e < e1; e += 256) {
        int d = dst[e];
        int s = src[e];
        int b = d >> BKT_SHIFT;
        int p = atomicAdd(&lcur[b], 1);
        sorted[p] = (unsigned)(s & 0xFFFF) | ((unsigned)(d & (BKT_NODES - 1)) << 16)
                  | ((unsigned)b << 24);
    }
    __syncthreads();
    int cnt = e1 - e0;
    for (int j = t; j < cnt; j += 256) {
        unsigned pk = sorted[j];
        int b = pk >> 24;
        bdata[gbase[b] + (j - lbase[b])] = pk;
    }
}

__global__ __launch_bounds__(256) void bucket_sort_rp(const int* __restrict__ bbase,
                                                      const unsigned* __restrict__ bdata,
                                                      int* __restrict__ row_ptr,
                                                      int* __restrict__ col,
                                                      int n_nodes, int n_edges, int nbk) {
    __shared__ int lcnt[BKT_NODES];
    __shared__ int lcur[BKT_NODES];
    int b = blockIdx.x;
    int t = threadIdx.x;
    int node0 = b << BKT_SHIFT;
    int nloc = min(BKT_NODES, n_nodes - node0);
    int base = bbase[b];
    int next = (b + 1 < nbk) ? bbase[b + 1] : n_edges;
    int cnt = next - base;
    lcnt[t] = 0;
    __syncthreads();
    for (int i = t; i < cnt; i += 256)
        atomicAdd(&lcnt[(bdata[base + i] >> 16) & 255], 1);
    __syncthreads();
    int v = lcnt[t];
    lcur[t] = v;
    __syncthreads();
    for (int off = 1; off < 256; off <<= 1) {
        int u = (t >= off) ? lcur[t - off] : 0;
        __syncthreads();
        lcur[t] += u;
        __syncthreads();
    }
    int excl = lcur[t] - v;
    __syncthreads();
    lcur[t] = excl;
    if (t < nloc) row_ptr[node0 + t] = base + excl;
    if (b == nbk - 1 && t == 0) row_ptr[n_nodes] = n_edges;
    __syncthreads();
    for (int i = t; i < cnt; i += 256) {
        unsigned pk = bdata[base + i];
        int pos = atomicAdd(&lcur[(pk >> 16) & 255], 1);
        col[base + pos] = pk & 0xFFFF;
    }
}

// ---------------- bf16 gather-side segment sum (bf16 output) ----------------
__global__ void aggregate_bf(const uint4* __restrict__ feat_bf,   // [N][16] uint4
                             const int* __restrict__ row_ptr,
                             const int* __restrict__ col,
                             uint4* __restrict__ out_bf,          // [N][16] uint4 (bf16)
                             int n_nodes) {
    int wid  = (blockIdx.x * blockDim.x + threadIdx.x) >> 6;
    int lane = threadIdx.x & 63;
    if (wid >= n_nodes) return;
    int sub = lane >> 4;            // edge slot 0..3
    int d   = lane & 15;            // 16B chunk within row
    int beg = row_ptr[wid];
    int end = row_ptr[wid + 1];
    float acc[8] = {0.f,0.f,0.f,0.f,0.f,0.f,0.f,0.f};

    int e = beg + sub;
    for (; e + 4 < end; e += 8) {
        int s0 = col[e];
        int s1 = col[e + 4];
        uint4 a = feat_bf[(size_t)s0 * 16 + d];
        uint4 b = feat_bf[(size_t)s1 * 16 + d];
        unsigned aw[4] = {a.x, a.y, a.z, a.w};
        unsigned bw[4] = {b.x, b.y, b.z, b.w};
#pragma unroll
        for (int j = 0; j < 4; ++j) {
            acc[2*j]   += __uint_as_float(aw[j] << 16);
            acc[2*j+1] += __uint_as_float(aw[j] & 0xFFFF0000u);
            acc[2*j]   += __uint_as_float(bw[j] << 16);
            acc[2*j+1] += __uint_as_float(bw[j] & 0xFFFF0000u);
        }
    }
    for (; e < end; e += 4) {
        int s0 = col[e];
        uint4 a = feat_bf[(size_t)s0 * 16 + d];
        unsigned aw[4] = {a.x, a.y, a.z, a.w};
#pragma unroll
        for (int j = 0; j < 4; ++j) {
            acc[2*j]   += __uint_as_float(aw[j] << 16);
            acc[2*j+1] += __uint_as_float(aw[j] & 0xFFFF0000u);
        }
    }
#pragma unroll
    for (int j = 0; j < 8; ++j) {
        acc[j] += __shfl_xor(acc[j], 16, 64);
        acc[j] += __shfl_xor(acc[j], 32, 64);
    }
    if (sub == 0) {
        uint4 pk;
        pk.x = pack_bf2(acc[0], acc[1]);
        pk.y = pack_bf2(acc[2], acc[3]);
        pk.z = pack_bf2(acc[4], acc[5]);
        pk.w = pack_bf2(acc[6], acc[7]);
        out_bf[(size_t)wid * 16 + d] = pk;
    }
}

// ---------------- bf16 MFMA linear: out = h @ W^T + b ----------------
// Block = 128 rows x 128 cols, 4 waves; wave owns 32 rows (2 row-frags).
// A frag: lane holds h[r0+(l&15)][kc+(l>>4)*8 .. +7]  (16B global load)
// B frag: lane holds W[c*16+(l&15)][kc+(l>>4)*8 .. +7] (W is [out][in] bf16)
// D = A.B^T per mfma_f32_16x16x32_bf16; C/D: col=lane&15, row=(lane>>4)*4+reg.
template <bool RELU, bool OUTBF>
__global__ __launch_bounds__(256) void linear_mfma(const unsigned short* __restrict__ h_bf,
                                                   const unsigned short* __restrict__ w_bf,
                                                   const float* __restrict__ bias,
                                                   float* __restrict__ out_f,
                                                   unsigned short* __restrict__ out_bf,
                                                   int n_nodes) {
    int t = threadIdx.x;
    int lane = t & 63;
    int wv = t >> 6;                       // 0..3
    int r0 = blockIdx.x * 128 + wv * 32;
    int n1 = n_nodes - 1;
    int ra0 = min(r0 + (lane & 15), n1);   // clamped A rows
    int ra1 = min(r0 + 16 + (lane & 15), n1);
    int kb = (lane >> 4) * 8;
    int colb = lane & 15;

    f32x4 acc[2][8];
#pragma unroll
    for (int fr = 0; fr < 2; ++fr)
#pragma unroll
        for (int c = 0; c < 8; ++c)
            acc[fr][c] = (f32x4){0.f, 0.f, 0.f, 0.f};

#pragma unroll
    for (int kc = 0; kc < NDIM; kc += 32) {
        bf16x8 a0 = *reinterpret_cast<const bf16x8*>(h_bf + (size_t)ra0 * NDIM + kc + kb);
        bf16x8 a1 = *reinterpret_cast<const bf16x8*>(h_bf + (size_t)ra1 * NDIM + kc + kb);
#pragma unroll
        for (int c = 0; c < 8; ++c) {
            bf16x8 b = *reinterpret_cast<const bf16x8*>(
                w_bf + (size_t)(c * 16 + colb) * NDIM + kc + kb);
            acc[0][c] = __builtin_amdgcn_mfma_f32_16x16x32_bf16(a0, b, acc[0][c], 0, 0, 0);
            acc[1][c] = __builtin_amdgcn_mfma_f32_16x16x32_bf16(a1, b, acc[1][c], 0, 0, 0);
        }
    }

    int orow = (lane >> 4) * 4;
#pragma unroll
    for (int fr = 0; fr < 2; ++fr) {
#pragma unroll
        for (int c = 0; c < 8; ++c) {
            int colg = c * 16 + colb;
            float bv = bias[colg];
#pragma unroll
            for (int reg = 0; reg < 4; ++reg) {
                int row = r0 + fr * 16 + orow + reg;
                if (row >= n_nodes) continue;
                float v = acc[fr][c][reg] + bv;
                if (RELU) v = fmaxf(v, 0.f);
                if (OUTBF) out_bf[(size_t)row * NDIM + colg] = f2bf_rne(v);
                else       out_f[(size_t)row * NDIM + colg] = v;
            }
        }
    }
}

// ================= fallback CSR build + f32 path (safety only) =================
__global__ void hist_dst(const int* __restrict__ dst, int* __restrict__ counts, int n_edges) {
    int i = blockIdx.x * blockDim.x + threadIdx.x;
    if (i < n_edges) atomicAdd(&counts[dst[i]], 1);
}

__global__ __launch_bounds__(SCAN_BS) void scan_apply_fb(int* __restrict__ row_ptr,
                                                         int* __restrict__ cursor,
                                                         const int* __restrict__ block_sums,
                                                         int n, int nb) {
    int b = blockIdx.x;
    int i = b * SCAN_BS + threadIdx.x;
    int add = (b == 0) ? 0 : block_sums[b - 1];
    if (i < n) {
        int r = row_ptr[i] + add;
        row_ptr[i] = r;
        cursor[i]  = r;
    }
    if (i == 0) row_ptr[n] = block_sums[nb - 1];
}

__global__ void fill_csr(const int* __restrict__ src, const int* __restrict__ dst,
                         int* __restrict__ cursor, int* __restrict__ col, int n_edges) {
    int i = blockIdx.x * blockDim.x + threadIdx.x;
    if (i < n_edges) {
        int pos = atomicAdd(&cursor[dst[i]], 1);
        col[pos] = src[i];
    }
}

__global__ void transpose_w2(const float* __restrict__ W1, const float* __restrict__ W2,
                             float* __restrict__ WT1, float* __restrict__ WT2) {
    int tid = blockIdx.x * 256 + threadIdx.x;
    int which = tid >> 14;
    int t = tid & 16383;
    int o = t >> 7;
    int i = t & 127;
    if (which == 0) WT1[i * NDIM + o] = W1[o * NDIM + i];
    else            WT2[i * NDIM + o] = W2[o * NDIM + i];
}

__global__ void aggregate(const float* __restrict__ feat,
                          const int* __restrict__ row_ptr,
                          const int* __restrict__ col,
                          float* __restrict__ out, int n_nodes) {
    int wid  = (blockIdx.x * blockDim.x + threadIdx.x) >> 6;
    int lane = threadIdx.x & 63;
    if (wid >= n_nodes) return;
    int half = lane >> 5;
    int d4   = (lane & 31) << 2;
    int beg = row_ptr[wid];
    int end = row_ptr[wid + 1];
    float ax = 0.f, ay = 0.f, az = 0.f, aw = 0.f;
    int k = beg + half;
    for (; k < end; k += 2) {
        int s0 = col[k];
        float4 v0 = *reinterpret_cast<const float4*>(feat + (size_t)s0 * NDIM + d4);
        ax += v0.x; ay += v0.y; az += v0.z; aw += v0.w;
    }
    ax += __shfl(ax, lane ^ 32, 64);
    ay += __shfl(ay, lane ^ 32, 64);
    az += __shfl(az, lane ^ 32, 64);
    aw += __shfl(aw, lane ^ 32, 64);
    if (half == 0) {
        float4 r; r.x = ax; r.y = ay; r.z = az; r.w = aw;
        *reinterpret_cast<float4*>(out + (size_t)wid * NDIM + d4) = r;
    }
}

template <bool RELU>
__global__ void linear_k(const float* __restrict__ h, const float* __restrict__ WT,
                         const float* __restrict__ bias, float* __restrict__ out,
                         int n_nodes) {
    int tid = blockIdx.x * blockDim.x + threadIdx.x;
    int row = tid >> 5;
    if (row >= n_nodes) return;
    int c4 = (tid & 31) << 2;
    const float4* h4 = reinterpret_cast<const float4*>(h + (size_t)row * NDIM);
    float4 acc = make_float4(0.f, 0.f, 0.f, 0.f);
#pragma unroll 8
    for (int k4 = 0; k4 < 32; ++k4) {
        float4 hv = h4[k4];
        const float* wt = WT + (k4 * 4) * NDIM + c4;
        float4 w0 = *reinterpret_cast<const float4*>(wt);
        float4 w1 = *reinterpret_cast<const float4*>(wt + NDIM);
        float4 w2 = *reinterpret_cast<const float4*>(wt + 2 * NDIM);
        float4 w3 = *reinterpret_cast<const float4*>(wt + 3 * NDIM);
        acc.x = fmaf(hv.x, w0.x, acc.x); acc.y = fmaf(hv.x, w0.y, acc.y);
        acc.z = fmaf(hv.x, w0.z, acc.z); acc.w = fmaf(hv.x, w0.w, acc.w);
        acc.x = fmaf(hv.y, w1.x, acc.x); acc.y = fmaf(hv.y, w1.y, acc.y);
        acc.z = fmaf(hv.y, w1.z, acc.z); acc.w = fmaf(hv.y, w1.w, acc.w);
        acc.x = fmaf(hv.z, w2.x, acc.x); acc.y = fmaf(hv.z, w2.y, acc.y);
        acc.z = fmaf(hv.z, w2.z, acc.z); acc.w = fmaf(hv.z, w2.w, acc.w);
        acc.x = fmaf(hv.w, w3.x, acc.x); acc.y = fmaf(hv.w, w3.y, acc.y);
        acc.z = fmaf(hv.w, w3.z, acc.z); acc.w = fmaf(hv.w, w3.w, acc.w);
    }
    float4 bv = *reinterpret_cast<const float4*>(bias + c4);
    acc.x += bv.x; acc.y += bv.y; acc.z += bv.z; acc.w += bv.w;
    if (RELU) {
        acc.x = fmaxf(acc.x, 0.f); acc.y = fmaxf(acc.y, 0.f);
        acc.z = fmaxf(acc.z, 0.f); acc.w = fmaxf(acc.w, 0.f);
    }
    *reinterpret_cast<float4*>(out + (size_t)row * NDIM + c4) = acc;
}

extern "C" void kernel_launch(void* const* d_in, const int* in_sizes, int n_in,
                              void* d_out, int out_size, void* d_ws, size_t ws_size,
                              hipStream_t stream) {
    const float* features = (const float*)d_in[0];
    const int*   src      = (const int*)d_in[1];
    const int*   dst      = (const int*)d_in[2];
    const float* W1       = (const float*)d_in[3];
    const float* b1       = (const float*)d_in[4];
    const float* W2       = (const float*)d_in[5];
    const float* b2       = (const float*)d_in[6];
    float* out = (float*)d_out;

    int n_nodes = in_sizes[0] / NDIM;   // 50000
    int n_edges = in_sizes[1];          // 800000
    int nbk = (n_nodes + BKT_NODES - 1) >> BKT_SHIFT;   // 196
    int ntiles = (n_edges + TILE - 1) / TILE;           // 196
    int rp_pad = ((n_nodes + 1 + 3) / 4) * 4;           // row_ptr padded to 16B

    // ---- ws layout (16B-aligned segments) ----
    char* base = (char*)d_ws;
    unsigned short* hneigh_bf = (unsigned short*)base;                     // N*128 bf16
    unsigned short* w1_bf  = hneigh_bf + (size_t)n_nodes * NDIM;           // 16384
    unsigned short* w2_bf  = w1_bf + NDIM * NDIM;                          // 16384
    int*   row_ptr = (int*)(w2_bf + NDIM * NDIM);                          // rp_pad
    int*   col     = row_ptr + rp_pad;                                     // E
    unsigned short* feat_bf = (unsigned short*)(col + n_edges);            // N*128 bf16
    int*      hist_g = (int*)(feat_bf + (size_t)n_nodes * NDIM);           // nbk*ntiles
    int*      bbase  = hist_g + (size_t)nbk * ntiles;                      // nbk (196)
    int*      tsums  = bbase + ((nbk + 3) / 4) * 4;                        // 128
    unsigned* bdata  = (unsigned*)(tsums + 128);                           // E
    // fallback-only buffers
    float* WT1    = (float*)(bdata + n_edges);                             // 16384
    float* WT2    = WT1 + NDIM * NDIM;                                     // 16384
    int*   counts = (int*)(WT2 + NDIM * NDIM);                             // N
    int*   cursor = counts + n_nodes;                                      // N
    float* hneigh_f = (float*)(cursor + n_nodes);                          // N*128 f32

    size_t needed_fast = (char*)(bdata + n_edges) - base;
    size_t needed_fb   = (char*)(hneigh_f + (size_t)n_nodes * NDIM) - base;

    unsigned short* h1_bf = (unsigned short*)d_out;   // h1 bf16 in d_out storage

    int eb = (n_edges + 255) / 256;
    int nscan = nbk * ntiles;
    int nsb = (nscan + SCAN_BS - 1) / SCAN_BS;
    bool fast = (ws_size >= needed_fast) && (n_nodes <= 65536)
              && (nbk <= NBK_MAX) && (nsb <= 128);

    if (fast) {
        int n8 = n_nodes * (NDIM / 8);
        convert_all<<<(n8 + 4096 + 255) / 256, 256, 0, stream>>>(
            features, W1, W2, feat_bf, w1_bf, w2_bf, n8);

        // ---- CSR build ----
        tile_hist<<<ntiles, 256, 0, stream>>>(dst, hist_g, n_edges, ntiles, nbk);
        scan_g_local<<<nsb, SCAN_BS, 0, stream>>>(hist_g, tsums, nscan);
        scan_blocksums<<<1, 128, 0, stream>>>(tsums, nsb);
        scan_g_apply<<<nsb, SCAN_BS, 0, stream>>>(hist_g, tsums, bbase, nscan, ntiles, nbk);
        tile_scatter<<<ntiles, 256, 0, stream>>>(src, dst, hist_g, bdata,
                                                 n_edges, ntiles, nbk);
        bucket_sort_rp<<<nbk, 256, 0, stream>>>(bbase, bdata, row_ptr, col,
                                                n_nodes, n_edges, nbk);

        int ab = (int)(((long)n_nodes * 64 + 255) / 256);
        int lb = (n_nodes + 127) / 128;

        // ---- Layer 1 ----
        aggregate_bf<<<ab, 256, 0, stream>>>((const uint4*)feat_bf, row_ptr, col,
                                             (uint4*)hneigh_bf, n_nodes);
        linear_mfma<true, true><<<lb, 256, 0, stream>>>(hneigh_bf, w1_bf, b1,
                                                        nullptr, h1_bf, n_nodes);
        // ---- Layer 2 ----
        aggregate_bf<<<ab, 256, 0, stream>>>((const uint4*)h1_bf, row_ptr, col,
                                             (uint4*)hneigh_bf, n_nodes);
        linear_mfma<false, false><<<lb, 256, 0, stream>>>(hneigh_bf, w2_bf, b2,
                                                          out, nullptr, n_nodes);
    } else if (ws_size >= needed_fb) {
        // ---- f32 fallback (round-5-style, safety only) ----
        transpose_w2<<<128, 256, 0, stream>>>(W1, W2, WT1, WT2);
        hipMemsetAsync(counts, 0, (size_t)n_nodes * sizeof(int), stream);
        hist_dst<<<eb, 256, 0, stream>>>(dst, counts, n_edges);
        int nb = (n_nodes + SCAN_BS - 1) / SCAN_BS;
        scan_g_local<<<nb, SCAN_BS, 0, stream>>>(counts, tsums, n_nodes);
        // counts now holds local-exclusive prefixes; rebuild row_ptr via apply
        scan_blocksums<<<1, 128, 0, stream>>>(tsums, nb);
        // copy counts->row_ptr with offsets + cursor
        scan_apply_fb<<<nb, SCAN_BS, 0, stream>>>(counts, cursor, tsums, n_nodes, nb);
        // counts[] now = global exclusive prefix = row_ptr values
        hipMemcpyAsync(row_ptr, counts, (size_t)(n_nodes + 1) * sizeof(int),
                       hipMemcpyDeviceToDevice, stream);
        fill_csr<<<eb, 256, 0, stream>>>(src, dst, cursor, col, n_edges);

        int ab = (int)(((long)n_nodes * 64 + 255) / 256);
        int lk = (n_nodes * 32 + 255) / 256;
        aggregate<<<ab, 256, 0, stream>>>(features, row_ptr, col, hneigh_f, n_nodes);
        linear_k<true><<<lk, 256, 0, stream>>>(hneigh_f, WT1, b1, out, n_nodes);
        aggregate<<<ab, 256, 0, stream>>>(out, row_ptr, col, hneigh_f, n_nodes);
        linear_k<false><<<lk, 256, 0, stream>>>(hneigh_f, WT2, b2, out, n_nodes);
    }
}